// Round 9
// baseline (206.372 us; speedup 1.0000x reference)
//
#include <hip/hip_runtime.h>
#include <stdint.h>

// Problem constants
#define IM_HW   16384            // 128*128 pixels
#define NBINS   33120            // 184*180
#define NMAPS   32               // b*c = 2*16
#define INV_NORM (1.0f / 128.0f)

#define BBITS   4                // bins per bucket = 16
#define NBUCK   2070             // NBINS/16 exactly
#define CAPB    2304             // slots/bucket (mean 1932, +8.4 sigma), %4==0
#define SLAB    192              // LDS slots per fine bin (mean 120.8, +6.5 sigma)
#define SSTR    196              // slab stride words (%4==0: 16B-aligned b128 reads)
#define NB_SCAT 256              // scatter blocks
#define NB_SPMM 2048             // spmm worker blocks (8/CU, work-stealing)
#define OVR_CAP 8192             // overflow list capacity (votes)
#define WQS     8191.0f          // 13-bit weight quantization scale

// ---------- x[32][16384] -> xT[16384][32] (gather rows become 128B contig) ----
__global__ __launch_bounds__(1024) void k_transpose_x(const float* __restrict__ x,
                                                      float* __restrict__ xT) {
  int i = blockIdx.x * 1024 + threadIdx.x;   // i = p*32 + m  (write-coalesced)
  int m = i & 31, p = i >> 5;
  xT[i] = x[m * IM_HW + p];
}

// ---------- bucket scatter: rank -> local scan -> LDS sort -> clustered flush --
// 1 LDS atomic/vote; per-(block,bucket) contiguous flush runs.
__global__ __launch_bounds__(1024) void k_scatter_bucket(
    const int* __restrict__ vp, const int* __restrict__ vb,
    const float* __restrict__ vw, int nv,
    unsigned* __restrict__ globcur,      // [NBUCK] bucket fills (pre-zeroed)
    unsigned* __restrict__ ovrcnt,       // [1] overflow count (pre-zeroed)
    uint2*   __restrict__ ovrlist,       // [OVR_CAP]
    unsigned* __restrict__ sorted) {     // [NBUCK*CAPB] 4B entries
  __shared__ unsigned h[NBUCK];          // per-bucket counts
  __shared__ unsigned lstart[NBUCK];     // local exclusive starts
  __shared__ unsigned cur[NBUCK];        // global reserved bases
  __shared__ unsigned sc[1024];          // scan temp
  __shared__ unsigned lds[16384];        // block-local bucket-sorted votes (64KB)

  const int tid = threadIdx.x;
  const int chunk = (((nv + NB_SCAT - 1) / NB_SCAT) + 3) & ~3;   // 4-aligned
  const int c0 = blockIdx.x * chunk;
  const int c1 = min(nv, c0 + chunk);
  const int cnt = (c1 > c0) ? (c1 - c0) : 0;    // <= 15628 <= 16384

  for (int i = tid; i < NBUCK; i += 1024) h[i] = 0u;
  __syncthreads();

  // stage + rank (1 LDS atomic per vote; return value = within-bucket rank)
  unsigned e[16];
  unsigned short rr[16], bu16[16];
  const int ng = cnt >> 2;                       // groups of 4 votes
  const int4*   vp4 = (const int4*)(vp + c0);
  const int4*   vb4 = (const int4*)(vb + c0);
  const float4* vw4 = (const float4*)(vw + c0);
  #pragma unroll
  for (int j = 0; j < 4; ++j) {
    const int g = tid + j * 1024;
    if (g < ng) {
      const int4 p = vp4[g]; const int4 b = vb4[g]; const float4 w = vw4[g];
      const int k = j * 4;
      #define STAGE(q, PP, BB, WW) { \
        const unsigned wq = (unsigned)((WW) * WQS + 0.5f); \
        e[k + q] = (unsigned)(PP) | (((unsigned)(BB) & 15u) << 14) | (wq << 18); \
        bu16[k + q] = (unsigned short)((unsigned)(BB) >> BBITS); \
        rr[k + q] = (unsigned short)atomicAdd(&h[(unsigned)(BB) >> BBITS], 1u); }
      STAGE(0, p.x, b.x, w.x) STAGE(1, p.y, b.y, w.y)
      STAGE(2, p.z, b.z, w.z) STAGE(3, p.w, b.w, w.w)
      #undef STAGE
    }
  }
  // robustness tail (cnt%4, zero for nv=4M): straight to overflow list
  const int tail0 = ng * 4;
  if (tid < cnt - tail0) {
    const int gi = c0 + tail0 + tid;
    unsigned o = atomicAdd(ovrcnt, 1u);
    if (o < OVR_CAP)
      ovrlist[o] = make_uint2((unsigned)vp[gi] | ((unsigned)vb[gi] << 14),
                              __float_as_uint(vw[gi]));
  }
  __syncthreads();

  // block-local exclusive scan of h -> lstart (3 buckets/thread, HS-1024)
  {
    const int i0 = 3 * tid;
    const unsigned a0 = (i0     < NBUCK) ? h[i0]     : 0u;
    const unsigned a1 = (i0 + 1 < NBUCK) ? h[i0 + 1] : 0u;
    const unsigned a2 = (i0 + 2 < NBUCK) ? h[i0 + 2] : 0u;
    const unsigned s3 = a0 + a1 + a2;
    sc[tid] = s3;
    __syncthreads();
    for (int d = 1; d < 1024; d <<= 1) {
      const unsigned v = (tid >= d) ? sc[tid - d] : 0u;
      __syncthreads();
      sc[tid] += v;
      __syncthreads();
    }
    const unsigned base = sc[tid] - s3;          // exclusive over triples
    if (i0     < NBUCK) lstart[i0]     = base;
    if (i0 + 1 < NBUCK) lstart[i0 + 1] = base + a0;
    if (i0 + 2 < NBUCK) lstart[i0 + 2] = base + a0 + a1;
  }
  // one global reservation per non-empty bucket
  for (int i = tid; i < NBUCK; i += 1024)
    cur[i] = (h[i] != 0u) ? atomicAdd(&globcur[i], h[i]) : 0u;
  __syncthreads();

  // place into LDS, bucket-clustered (plain b32 writes; rank from registers)
  #pragma unroll
  for (int j = 0; j < 4; ++j) {
    const int g = tid + j * 1024;
    if (g < ng) {
      #pragma unroll
      for (int q = 0; q < 4; ++q) {
        const int k = j * 4 + q;
        lds[lstart[bu16[k]] + (unsigned)rr[k]] = e[k];
      }
    }
  }
  __syncthreads();

  // flush: wave w -> buckets w, w+16, ...; contiguous LDS -> contiguous global
  const int wid = tid >> 6, lane = tid & 63;
  for (int bu = wid; bu < NBUCK; bu += 16) {
    const unsigned c = h[bu];
    if (c == 0u) continue;                       // wave-uniform branch
    const unsigned gb = cur[bu], lb = lstart[bu];
    for (unsigned s = lane; s < c; s += 64) {
      const unsigned E = lds[lb + s];
      const unsigned g = gb + s;
      if (g < CAPB) {
        sorted[(size_t)bu * CAPB + g] = E;
      } else {
        unsigned o = atomicAdd(ovrcnt, 1u);
        if (o < OVR_CAP) {
          const unsigned pp  = E & 0x3FFFu;
          const unsigned bin = ((unsigned)bu << BBITS) + ((E >> 14) & 15u);
          const float    wf  = (float)(E >> 18) * (1.0f / WQS);
          ovrlist[o] = make_uint2(pp | (bin << 14), __float_as_uint(wf));
        }
      }
    }
  }
}

// ---------- per-bucket spmm: work-stealing persistent blocks ------------------
// placement (1 atomic + b32/vote) into 16 slabs, then per-bin wave register
// accumulation; b128 LDS reads (8 votes per wave-instr).
__global__ __launch_bounds__(256) void k_spmm_static(
    const unsigned* __restrict__ sorted, const unsigned* __restrict__ globcur,
    const float* __restrict__ xT, float* __restrict__ outT,
    unsigned* __restrict__ ovrcnt, uint2* __restrict__ ovrlist,
    unsigned* __restrict__ wsctr) {
  __shared__ unsigned sv[16 * SSTR];       // 12,544 B -> 8 blocks/CU (wave cap)
  __shared__ unsigned cur[16];
  __shared__ int bu_s;
  const int tid = threadIdx.x;

  for (;;) {
    if (tid == 0) bu_s = (int)atomicAdd(wsctr, 1u);
    __syncthreads();
    const int bu = bu_s;
    if (bu >= NBUCK) return;
    if (tid < 16) cur[tid] = 0u;
    __syncthreads();

    const int n = min((int)globcur[bu], CAPB);

    // place: 4 votes per 16B load, 1 LDS atomic + 1 b32 write per vote
    const uint4* src = (const uint4*)(sorted + (size_t)bu * CAPB);  // CAPB%4==0
    const int nq = n >> 2;
    #define PLACE(E) { \
      const unsigned fb = ((E) >> 14) & 15u; \
      const unsigned s = atomicAdd(&cur[fb], 1u); \
      if (s < SLAB) sv[fb * SSTR + s] = (E); \
      else { \
        unsigned o = atomicAdd(ovrcnt, 1u); \
        if (o < OVR_CAP) \
          ovrlist[o] = make_uint2(((E) & 0x3FFFu) | ((((unsigned)bu << BBITS) + fb) << 14), \
                                  __float_as_uint((float)((E) >> 18) * (1.0f / WQS))); } }
    for (int i = tid; i < nq; i += 256) {
      const uint4 q = src[i];
      PLACE(q.x) PLACE(q.y) PLACE(q.z) PLACE(q.w)
    }
    if (tid < (n & 3)) {                   // tail votes (<=3)
      const unsigned E = sorted[(size_t)bu * CAPB + (n & ~3) + tid];
      PLACE(E)
    }
    #undef PLACE
    __syncthreads();

    // compute: wave wv -> bins [wv*4, wv*4+4); halves read uint4 (4 votes)
    // per iter via one ds_read_b128 (SSTR%4==0 => 16B-aligned).
    const int wv = tid >> 6, lane = tid & 63, half = lane >> 5, m = lane & 31;
    #pragma unroll
    for (int s4 = 0; s4 < 4; ++s4) {
      const int b = wv * 4 + s4;
      const int cnt = min((int)cur[b], SLAB);
      const unsigned* seg = &sv[b * SSTR];
      float acc = 0.0f;                    // accumulates wq * x (scaled at end)
      int base = 0;
      for (; base + 8 <= cnt; base += 8) {
        const uint4 a = *(const uint4*)(seg + base + 4 * half);
        acc += (float)(a.x >> 18) * xT[(a.x & 0x3FFFu) * 32 + m];
        acc += (float)(a.y >> 18) * xT[(a.y & 0x3FFFu) * 32 + m];
        acc += (float)(a.z >> 18) * xT[(a.z & 0x3FFFu) * 32 + m];
        acc += (float)(a.w >> 18) * xT[(a.w & 0x3FFFu) * 32 + m];
      }
      for (; base + 4 <= cnt; base += 4) {
        const uint2 a = *(const uint2*)(seg + base + 2 * half);
        acc += (float)(a.x >> 18) * xT[(a.x & 0x3FFFu) * 32 + m];
        acc += (float)(a.y >> 18) * xT[(a.y & 0x3FFFu) * 32 + m];
      }
      if (half == 0) {                     // scalar tail (<=3 votes)
        for (int j = base; j < cnt; ++j) {
          const unsigned E = seg[j];
          acc += (float)(E >> 18) * xT[(E & 0x3FFFu) * 32 + m];
        }
      }
      acc += __shfl_xor(acc, 32);          // combine halves
      if (lane < 32)                       // 128B coalesced store
        outT[(size_t)((bu << BBITS) + b) * 32 + m] = acc * ((1.0f / WQS) * INV_NORM);
    }
    __syncthreads();                       // protect sv/cur/bu_s for next bucket
  }
}

// ---------- rare overflow votes: direct global atomic into outT ----------------
__global__ __launch_bounds__(1024) void k_overflow(
    const uint2* __restrict__ ovrlist, const unsigned* __restrict__ ovrcnt,
    const float* __restrict__ xT, float* __restrict__ outT) {
  unsigned nz = *ovrcnt;
  unsigned n = nz < (unsigned)OVR_CAP ? nz : (unsigned)OVR_CAP;
  unsigned total = n * 32u;
  for (unsigned i = blockIdx.x * 1024u + threadIdx.x; i < total;
       i += gridDim.x * 1024u) {
    unsigned vi = i >> 5, m = i & 31u;
    uint2 vv = ovrlist[vi];
    unsigned p = vv.x & 0x3FFFu, bin = vv.x >> 14;
    atomicAdd(&outT[(size_t)bin * 32 + m],
              __uint_as_float(vv.y) * xT[p * 32 + m] * INV_NORM);
  }
}

// ---------- outT[33120][32] -> out[32][33120] (LDS tile transpose) ------------
__global__ __launch_bounds__(1024) void k_transpose_out(const float* __restrict__ outT,
                                                        float* __restrict__ out) {
  __shared__ float tile[32][33];
  const int tx = threadIdx.x & 31, ty = threadIdx.x >> 5;
  const int b0 = blockIdx.x * 32;            // NBINS = 1035*32
  tile[ty][tx] = outT[(b0 + ty) * 32 + tx];  // coalesced read
  __syncthreads();
  out[ty * NBINS + b0 + tx] = tile[tx][ty];  // coalesced write, stride-33 LDS
}

// ---------- fallback (ws too small): R1 LDS-histogram version -----------------
__global__ __launch_bounds__(1024) void ht_fallback(const float* __restrict__ x,
                                                    const int* __restrict__ vp,
                                                    const int* __restrict__ vb,
                                                    const float* __restrict__ vw,
                                                    float* __restrict__ out, int nv) {
  __shared__ float hist[NBINS];
  for (int i = threadIdx.x; i < NBINS; i += 1024) hist[i] = 0.0f;
  __syncthreads();
  const int map = blockIdx.x >> 3, chunk = blockIdx.x & 7;
  const float* xm = x + map * IM_HW;
  const int per = (nv + 7) / 8;
  const int start = chunk * per, end = min(nv, start + per);
  for (int i = start + (int)threadIdx.x; i < end; i += 1024)
    atomicAdd(&hist[vb[i]], xm[vp[i]] * vw[i]);
  __syncthreads();
  float* om = out + map * NBINS;
  for (int i = threadIdx.x; i < NBINS; i += 1024)
    atomicAdd(&om[i], hist[i] * INV_NORM);
}

extern "C" void kernel_launch(void* const* d_in, const int* in_sizes, int n_in,
                              void* d_out, int out_size, void* d_ws, size_t ws_size,
                              hipStream_t stream) {
  const float* x  = (const float*)d_in[0];
  const int*   vp = (const int*)d_in[1];
  const int*   vb = (const int*)d_in[2];
  const float* vw = (const float*)d_in[3];
  float* out = (float*)d_out;
  const int nv = in_sizes[1];

  // ws layout (all sections 16B-aligned)
  char* w = (char*)d_ws;
  unsigned* sorted  = (unsigned*)w; w += (size_t)NBUCK * CAPB * 4;   // 19.1 MB
  float*    xT      = (float*)w;    w += (size_t)IM_HW * NMAPS * 4;  // 2 MB
  float*    outT    = (float*)w;    w += (size_t)NBINS * NMAPS * 4;  // 4.2 MB
  uint2*    ovrlist = (uint2*)w;    w += (size_t)OVR_CAP * 8;        // 64 KB
  unsigned* globcur = (unsigned*)w; w += (size_t)NBUCK * 4;          // 8280 B
  unsigned* ovrcnt  = (unsigned*)w; w += 4;
  unsigned* wsctr   = (unsigned*)w; w += 12;                         // pad to 16
  const size_t need = (size_t)(w - (char*)d_ws);

  if (ws_size >= need) {
    // zero globcur + ovrcnt + wsctr (one contiguous region)
    hipMemsetAsync(globcur, 0, (size_t)NBUCK * 4 + 16, stream);
    k_transpose_x<<<(IM_HW * NMAPS) / 1024, 1024, 0, stream>>>(x, xT);
    k_scatter_bucket<<<NB_SCAT, 1024, 0, stream>>>(vp, vb, vw, nv, globcur,
                                                   ovrcnt, ovrlist, sorted);
    k_spmm_static<<<NB_SPMM, 256, 0, stream>>>(sorted, globcur, xT, outT,
                                               ovrcnt, ovrlist, wsctr);
    k_overflow<<<8, 1024, 0, stream>>>(ovrlist, ovrcnt, xT, outT);
    k_transpose_out<<<NBINS / 32, 1024, 0, stream>>>(outT, out);
  } else {
    hipMemsetAsync(out, 0, (size_t)out_size * sizeof(float), stream);
    ht_fallback<<<256, 1024, 0, stream>>>(x, vp, vb, vw, out, nv);
  }
}

// Round 10
// 172.590 us; speedup vs baseline: 1.1957x; 1.1957x over previous
//
#include <hip/hip_runtime.h>
#include <stdint.h>

// Problem constants
#define IM_HW   16384            // 128*128 pixels
#define NBINS   33120            // 184*180
#define NMAPS   32               // b*c = 2*16
#define INV_NORM (1.0f / 128.0f)

#define BBITS   5                // bins per bucket = 32
#define NBUCK   1035             // NBINS/32 exactly
#define CAPB    4352             // slots/bucket (mean 3865, +7.8 sigma), %4==0
#define SLAB    192              // LDS slots per fine bin (mean 120.8, +6.5 sigma)
#define SSTR    194              // slab stride (even: b64-aligned; ≡2 mod 32: bank spread)
#define NB_SCAT 256              // scatter blocks
#define NB_SPMM 1024             // spmm persistent blocks (4/CU resident)
#define OVR_CAP 8192             // overflow list capacity (votes)
#define WQS     8191.0f          // 13-bit weight quantization scale

// ---------- x[32][16384] -> xT[16384][32] (gather rows become 128B contig) ----
__global__ __launch_bounds__(1024) void k_transpose_x(const float* __restrict__ x,
                                                      float* __restrict__ xT) {
  int i = blockIdx.x * 1024 + threadIdx.x;   // i = p*32 + m  (write-coalesced)
  int m = i & 31, p = i >> 5;
  xT[i] = x[m * IM_HW + p];
}

// ---------- bucket scatter: rank -> local scan -> LDS sort -> clustered flush --
// (R8-proven form, BBITS=5) 1 LDS atomic/vote; contiguous per-bucket flush runs.
__global__ __launch_bounds__(1024) void k_scatter_bucket(
    const int* __restrict__ vp, const int* __restrict__ vb,
    const float* __restrict__ vw, int nv,
    unsigned* __restrict__ globcur,      // [NBUCK] bucket fills (pre-zeroed)
    unsigned* __restrict__ ovrcnt,       // [1] overflow count (pre-zeroed)
    uint2*   __restrict__ ovrlist,       // [OVR_CAP]
    unsigned* __restrict__ sorted) {     // [NBUCK*CAPB] 4B entries
  __shared__ unsigned h[NBUCK];          // per-bucket counts
  __shared__ unsigned lstart[NBUCK];     // local exclusive starts
  __shared__ unsigned cur[NBUCK];        // global reserved bases
  __shared__ unsigned sc[1024];          // scan temp
  __shared__ unsigned lds[16384];        // block-local bucket-sorted votes (64KB)

  const int tid = threadIdx.x;
  const int chunk = (((nv + NB_SCAT - 1) / NB_SCAT) + 3) & ~3;   // 4-aligned
  const int c0 = blockIdx.x * chunk;
  const int c1 = min(nv, c0 + chunk);
  const int cnt = (c1 > c0) ? (c1 - c0) : 0;    // <= 15628 <= 16384

  for (int i = tid; i < NBUCK; i += 1024) h[i] = 0u;
  __syncthreads();

  // stage + rank (1 LDS atomic per vote; return value = within-bucket rank)
  unsigned e[16];
  unsigned short rr[16], bu16[16];
  const int ng = cnt >> 2;                       // groups of 4 votes
  const int4*   vp4 = (const int4*)(vp + c0);
  const int4*   vb4 = (const int4*)(vb + c0);
  const float4* vw4 = (const float4*)(vw + c0);
  #pragma unroll
  for (int j = 0; j < 4; ++j) {
    const int g = tid + j * 1024;
    if (g < ng) {
      const int4 p = vp4[g]; const int4 b = vb4[g]; const float4 w = vw4[g];
      const int k = j * 4;
      #define STAGE(q, PP, BB, WW) { \
        const unsigned wq = (unsigned)((WW) * WQS + 0.5f); \
        e[k + q] = (unsigned)(PP) | (((unsigned)(BB) & 31u) << 14) | (wq << 19); \
        bu16[k + q] = (unsigned short)((unsigned)(BB) >> BBITS); \
        rr[k + q] = (unsigned short)atomicAdd(&h[(unsigned)(BB) >> BBITS], 1u); }
      STAGE(0, p.x, b.x, w.x) STAGE(1, p.y, b.y, w.y)
      STAGE(2, p.z, b.z, w.z) STAGE(3, p.w, b.w, w.w)
      #undef STAGE
    }
  }
  // robustness tail (cnt%4, zero for nv=4M): straight to overflow list
  const int tail0 = ng * 4;
  if (tid < cnt - tail0) {
    const int gi = c0 + tail0 + tid;
    unsigned o = atomicAdd(ovrcnt, 1u);
    if (o < OVR_CAP)
      ovrlist[o] = make_uint2((unsigned)vp[gi] | ((unsigned)vb[gi] << 14),
                              __float_as_uint(vw[gi]));
  }
  __syncthreads();

  // block-local exclusive scan of h -> lstart (2 buckets/thread, HS-1024)
  {
    const int i0 = 2 * tid, i1 = 2 * tid + 1;
    const unsigned a0 = (i0 < NBUCK) ? h[i0] : 0u;
    const unsigned a1 = (i1 < NBUCK) ? h[i1] : 0u;
    const unsigned s2 = a0 + a1;
    sc[tid] = s2;
    __syncthreads();
    for (int d = 1; d < 1024; d <<= 1) {
      const unsigned v = (tid >= d) ? sc[tid - d] : 0u;
      __syncthreads();
      sc[tid] += v;
      __syncthreads();
    }
    const unsigned base = sc[tid] - s2;          // exclusive over pairs
    if (i0 < NBUCK) lstart[i0] = base;
    if (i1 < NBUCK) lstart[i1] = base + a0;
  }
  // one global reservation per non-empty bucket
  for (int i = tid; i < NBUCK; i += 1024)
    cur[i] = (h[i] != 0u) ? atomicAdd(&globcur[i], h[i]) : 0u;
  __syncthreads();

  // place into LDS, bucket-clustered (plain b32 writes; rank from registers)
  #pragma unroll
  for (int j = 0; j < 4; ++j) {
    const int g = tid + j * 1024;
    if (g < ng) {
      #pragma unroll
      for (int q = 0; q < 4; ++q) {
        const int k = j * 4 + q;
        lds[lstart[bu16[k]] + (unsigned)rr[k]] = e[k];
      }
    }
  }
  __syncthreads();

  // flush: wave w -> buckets w, w+16, ...; contiguous LDS -> contiguous global
  const int wid = tid >> 6, lane = tid & 63;
  for (int bu = wid; bu < NBUCK; bu += 16) {
    const unsigned c = h[bu];
    if (c == 0u) continue;                       // wave-uniform branch
    const unsigned gb = cur[bu], lb = lstart[bu];
    for (unsigned s = lane; s < c; s += 64) {
      const unsigned E = lds[lb + s];
      const unsigned g = gb + s;
      if (g < CAPB) {
        sorted[(size_t)bu * CAPB + g] = E;
      } else {
        unsigned o = atomicAdd(ovrcnt, 1u);
        if (o < OVR_CAP) {
          const unsigned pp  = E & 0x3FFFu;
          const unsigned bin = ((unsigned)bu << BBITS) + ((E >> 14) & 31u);
          const float    wf  = (float)(E >> 19) * (1.0f / WQS);
          ovrlist[o] = make_uint2(pp | (bin << 14), __float_as_uint(wf));
        }
      }
    }
  }
}

// ---------- per-bucket spmm (R8-proven body) + work-stealing over buckets -----
// ONLY change vs R8: persistent blocks steal buckets from wsctr (grid 1024 =
// 4 blocks/CU resident) to kill the 4.04-blocks/CU straggler tail.
__global__ __launch_bounds__(512) void k_spmm_static(
    const unsigned* __restrict__ sorted, const unsigned* __restrict__ globcur,
    const float* __restrict__ xT, float* __restrict__ outT,
    unsigned* __restrict__ ovrcnt, uint2* __restrict__ ovrlist,
    unsigned* __restrict__ wsctr) {
  __shared__ unsigned sv[32 * SSTR];       // 24,832 B -> 4 blocks/CU (wave cap)
  __shared__ unsigned cur[32];
  __shared__ int bu_s;
  const int tid = threadIdx.x;

  for (;;) {
    if (tid == 0) bu_s = (int)atomicAdd(wsctr, 1u);
    __syncthreads();
    const int bu = bu_s;
    if (bu >= NBUCK) return;
    if (tid < 32) cur[tid] = 0u;
    __syncthreads();

    const int n = min((int)globcur[bu], CAPB);

    // place: 4 votes per 16B load, 1 LDS atomic + 1 b32 write per vote
    const uint4* src = (const uint4*)(sorted + (size_t)bu * CAPB);  // CAPB%4==0
    const int nq = n >> 2;
    #define PLACE(E) { \
      const unsigned fb = ((E) >> 14) & 31u; \
      const unsigned s = atomicAdd(&cur[fb], 1u); \
      if (s < SLAB) sv[fb * SSTR + s] = (E); \
      else { \
        unsigned o = atomicAdd(ovrcnt, 1u); \
        if (o < OVR_CAP) \
          ovrlist[o] = make_uint2(((E) & 0x3FFFu) | ((((unsigned)bu << BBITS) + fb) << 14), \
                                  __float_as_uint((float)((E) >> 19) * (1.0f / WQS))); } }
    for (int i = tid; i < nq; i += 512) {
      const uint4 q = src[i];
      PLACE(q.x) PLACE(q.y) PLACE(q.z) PLACE(q.w)
    }
    if (tid < (n & 3)) {                   // tail votes (<=3)
      const unsigned E = sorted[(size_t)bu * CAPB + (n & ~3) + tid];
      PLACE(E)
    }
    #undef PLACE
    __syncthreads();

    // compute: wave wv -> bins [wv*4, wv*4+4); halves take consecutive pairs
    // via ds_read_b64 (SSTR even => 8B aligned); 2 indep chains per iter.
    const int wv = tid >> 6, lane = tid & 63, half = lane >> 5, m = lane & 31;
    #pragma unroll
    for (int s4 = 0; s4 < 4; ++s4) {
      const int b = wv * 4 + s4;
      const int cnt = min((int)cur[b], SLAB);
      const unsigned* seg = &sv[b * SSTR];
      float acc = 0.0f;                    // accumulates wq * x (scaled at end)
      int base = 0;
      for (; base + 8 <= cnt; base += 8) {
        const uint2 a = *(const uint2*)(seg + base + 2 * half);
        const uint2 c = *(const uint2*)(seg + base + 4 + 2 * half);
        acc += (float)(a.x >> 19) * xT[(a.x & 0x3FFFu) * 32 + m];
        acc += (float)(a.y >> 19) * xT[(a.y & 0x3FFFu) * 32 + m];
        acc += (float)(c.x >> 19) * xT[(c.x & 0x3FFFu) * 32 + m];
        acc += (float)(c.y >> 19) * xT[(c.y & 0x3FFFu) * 32 + m];
      }
      for (; base + 4 <= cnt; base += 4) {
        const uint2 a = *(const uint2*)(seg + base + 2 * half);
        acc += (float)(a.x >> 19) * xT[(a.x & 0x3FFFu) * 32 + m];
        acc += (float)(a.y >> 19) * xT[(a.y & 0x3FFFu) * 32 + m];
      }
      if (half == 0) {                     // scalar tail (<=3 votes)
        for (int j = base; j < cnt; ++j) {
          const unsigned E = seg[j];
          acc += (float)(E >> 19) * xT[(E & 0x3FFFu) * 32 + m];
        }
      }
      acc += __shfl_xor(acc, 32);          // combine halves
      if (lane < 32)                       // 128B coalesced store
        outT[(size_t)((bu << BBITS) + b) * 32 + m] = acc * ((1.0f / WQS) * INV_NORM);
    }
    __syncthreads();                       // protect sv/cur/bu_s for next bucket
  }
}

// ---------- rare overflow votes: direct global atomic into outT ----------------
__global__ __launch_bounds__(1024) void k_overflow(
    const uint2* __restrict__ ovrlist, const unsigned* __restrict__ ovrcnt,
    const float* __restrict__ xT, float* __restrict__ outT) {
  unsigned nz = *ovrcnt;
  unsigned n = nz < (unsigned)OVR_CAP ? nz : (unsigned)OVR_CAP;
  unsigned total = n * 32u;
  for (unsigned i = blockIdx.x * 1024u + threadIdx.x; i < total;
       i += gridDim.x * 1024u) {
    unsigned vi = i >> 5, m = i & 31u;
    uint2 vv = ovrlist[vi];
    unsigned p = vv.x & 0x3FFFu, bin = vv.x >> 14;
    atomicAdd(&outT[(size_t)bin * 32 + m],
              __uint_as_float(vv.y) * xT[p * 32 + m] * INV_NORM);
  }
}

// ---------- outT[33120][32] -> out[32][33120] (LDS tile transpose) ------------
__global__ __launch_bounds__(1024) void k_transpose_out(const float* __restrict__ outT,
                                                        float* __restrict__ out) {
  __shared__ float tile[32][33];
  const int tx = threadIdx.x & 31, ty = threadIdx.x >> 5;
  const int b0 = blockIdx.x * 32;            // NBINS = 1035*32
  tile[ty][tx] = outT[(b0 + ty) * 32 + tx];  // coalesced read
  __syncthreads();
  out[ty * NBINS + b0 + tx] = tile[tx][ty];  // coalesced write, stride-33 LDS
}

// ---------- fallback (ws too small): R1 LDS-histogram version -----------------
__global__ __launch_bounds__(1024) void ht_fallback(const float* __restrict__ x,
                                                    const int* __restrict__ vp,
                                                    const int* __restrict__ vb,
                                                    const float* __restrict__ vw,
                                                    float* __restrict__ out, int nv) {
  __shared__ float hist[NBINS];
  for (int i = threadIdx.x; i < NBINS; i += 1024) hist[i] = 0.0f;
  __syncthreads();
  const int map = blockIdx.x >> 3, chunk = blockIdx.x & 7;
  const float* xm = x + map * IM_HW;
  const int per = (nv + 7) / 8;
  const int start = chunk * per, end = min(nv, start + per);
  for (int i = start + (int)threadIdx.x; i < end; i += 1024)
    atomicAdd(&hist[vb[i]], xm[vp[i]] * vw[i]);
  __syncthreads();
  float* om = out + map * NBINS;
  for (int i = threadIdx.x; i < NBINS; i += 1024)
    atomicAdd(&om[i], hist[i] * INV_NORM);
}

extern "C" void kernel_launch(void* const* d_in, const int* in_sizes, int n_in,
                              void* d_out, int out_size, void* d_ws, size_t ws_size,
                              hipStream_t stream) {
  const float* x  = (const float*)d_in[0];
  const int*   vp = (const int*)d_in[1];
  const int*   vb = (const int*)d_in[2];
  const float* vw = (const float*)d_in[3];
  float* out = (float*)d_out;
  const int nv = in_sizes[1];

  // ws layout (all sections 16B-aligned)
  char* w = (char*)d_ws;
  unsigned* sorted  = (unsigned*)w; w += (size_t)NBUCK * CAPB * 4;   // 18.0 MB
  float*    xT      = (float*)w;    w += (size_t)IM_HW * NMAPS * 4;  // 2 MB
  float*    outT    = (float*)w;    w += (size_t)NBINS * NMAPS * 4;  // 4.2 MB
  uint2*    ovrlist = (uint2*)w;    w += (size_t)OVR_CAP * 8;        // 64 KB
  unsigned* globcur = (unsigned*)w; w += (size_t)NBUCK * 4;          // 4140 B
  unsigned* ovrcnt  = (unsigned*)w; w += 4;
  unsigned* wsctr   = (unsigned*)w; w += 12;                         // pad to 16
  const size_t need = (size_t)(w - (char*)d_ws);

  if (ws_size >= need) {
    // zero globcur + ovrcnt + wsctr (one contiguous region)
    hipMemsetAsync(globcur, 0, (size_t)NBUCK * 4 + 16, stream);
    k_transpose_x<<<(IM_HW * NMAPS) / 1024, 1024, 0, stream>>>(x, xT);
    k_scatter_bucket<<<NB_SCAT, 1024, 0, stream>>>(vp, vb, vw, nv, globcur,
                                                   ovrcnt, ovrlist, sorted);
    k_spmm_static<<<NB_SPMM, 512, 0, stream>>>(sorted, globcur, xT, outT,
                                               ovrcnt, ovrlist, wsctr);
    k_overflow<<<8, 1024, 0, stream>>>(ovrlist, ovrcnt, xT, outT);
    k_transpose_out<<<NBINS / 32, 1024, 0, stream>>>(outT, out);
  } else {
    hipMemsetAsync(out, 0, (size_t)out_size * sizeof(float), stream);
    ht_fallback<<<256, 1024, 0, stream>>>(x, vp, vb, vw, out, nv);
  }
}

// Round 11
// 161.144 us; speedup vs baseline: 1.2807x; 1.0710x over previous
//
#include <hip/hip_runtime.h>
#include <stdint.h>

// Problem constants
#define IM_HW   16384            // 128*128 pixels
#define NBINS   33120            // 184*180
#define NMAPS   32               // b*c = 2*16
#define INV_NORM (1.0f / 128.0f)

#define BBITS   5                // bins per bucket = 32
#define NBUCK   1035             // NBINS/32 exactly
#define CAPB    4352             // slots/bucket (mean 3865, +7.8 sigma), %4==0
#define SLAB    192              // LDS slots per fine bin (mean 120.8, +6.5 sigma)
#define SSTR    194              // slab stride (even: b64-aligned; ≡2 mod 32: bank spread)
#define NB_SCAT 256              // scatter blocks
#define OVR_CAP 8192             // overflow list capacity (votes)
#define WQS     8191.0f          // 13-bit weight quantization scale

// ---------- bucket scatter (R8-proven) + fused xT transpose prologue ----------
// Prologue: 256 blocks x 2048 elems -> xT[16384][32]; consumed only by spmm
// (next kernel), so no intra-kernel barrier is needed.
// Then: rank -> local scan -> LDS sort -> clustered flush. 1 LDS atomic/vote.
__global__ __launch_bounds__(1024) void k_scatter_bucket(
    const float* __restrict__ x, float* __restrict__ xT,
    const int* __restrict__ vp, const int* __restrict__ vb,
    const float* __restrict__ vw, int nv,
    unsigned* __restrict__ globcur,      // [NBUCK] bucket fills (pre-zeroed)
    unsigned* __restrict__ ovrcnt,       // [1] overflow count (pre-zeroed)
    uint2*   __restrict__ ovrlist,       // [OVR_CAP]
    unsigned* __restrict__ sorted) {     // [NBUCK*CAPB] 4B entries
  __shared__ unsigned h[NBUCK];          // per-bucket counts
  __shared__ unsigned lstart[NBUCK];     // local exclusive starts
  __shared__ unsigned cur[NBUCK];        // global reserved bases
  __shared__ unsigned sc[1024];          // scan temp
  __shared__ unsigned lds[16384];        // block-local bucket-sorted votes (64KB)

  const int tid = threadIdx.x;

  // fused transpose: x[32][16384] -> xT[16384][32] (write-coalesced)
  {
    const int base = blockIdx.x * 2048;          // 256*2048 = 524288 = 32*16384
    #pragma unroll
    for (int k = 0; k < 2; ++k) {
      const int i = base + k * 1024 + tid;       // i = p*32 + m
      const int m = i & 31, p = i >> 5;
      xT[i] = x[m * IM_HW + p];
    }
  }

  const int chunk = (((nv + NB_SCAT - 1) / NB_SCAT) + 3) & ~3;   // 4-aligned
  const int c0 = blockIdx.x * chunk;
  const int c1 = min(nv, c0 + chunk);
  const int cnt = (c1 > c0) ? (c1 - c0) : 0;    // <= 15628 <= 16384

  for (int i = tid; i < NBUCK; i += 1024) h[i] = 0u;
  __syncthreads();

  // stage + rank (1 LDS atomic per vote; return value = within-bucket rank)
  unsigned e[16];
  unsigned short rr[16], bu16[16];
  const int ng = cnt >> 2;                       // groups of 4 votes
  const int4*   vp4 = (const int4*)(vp + c0);
  const int4*   vb4 = (const int4*)(vb + c0);
  const float4* vw4 = (const float4*)(vw + c0);
  #pragma unroll
  for (int j = 0; j < 4; ++j) {
    const int g = tid + j * 1024;
    if (g < ng) {
      const int4 p = vp4[g]; const int4 b = vb4[g]; const float4 w = vw4[g];
      const int k = j * 4;
      #define STAGE(q, PP, BB, WW) { \
        const unsigned wq = (unsigned)((WW) * WQS + 0.5f); \
        e[k + q] = (unsigned)(PP) | (((unsigned)(BB) & 31u) << 14) | (wq << 19); \
        bu16[k + q] = (unsigned short)((unsigned)(BB) >> BBITS); \
        rr[k + q] = (unsigned short)atomicAdd(&h[(unsigned)(BB) >> BBITS], 1u); }
      STAGE(0, p.x, b.x, w.x) STAGE(1, p.y, b.y, w.y)
      STAGE(2, p.z, b.z, w.z) STAGE(3, p.w, b.w, w.w)
      #undef STAGE
    }
  }
  // robustness tail (cnt%4, zero for nv=4M): straight to overflow list
  const int tail0 = ng * 4;
  if (tid < cnt - tail0) {
    const int gi = c0 + tail0 + tid;
    unsigned o = atomicAdd(ovrcnt, 1u);
    if (o < OVR_CAP)
      ovrlist[o] = make_uint2((unsigned)vp[gi] | ((unsigned)vb[gi] << 14),
                              __float_as_uint(vw[gi]));
  }
  __syncthreads();

  // block-local exclusive scan of h -> lstart (2 buckets/thread, HS-1024)
  {
    const int i0 = 2 * tid, i1 = 2 * tid + 1;
    const unsigned a0 = (i0 < NBUCK) ? h[i0] : 0u;
    const unsigned a1 = (i1 < NBUCK) ? h[i1] : 0u;
    const unsigned s2 = a0 + a1;
    sc[tid] = s2;
    __syncthreads();
    for (int d = 1; d < 1024; d <<= 1) {
      const unsigned v = (tid >= d) ? sc[tid - d] : 0u;
      __syncthreads();
      sc[tid] += v;
      __syncthreads();
    }
    const unsigned base = sc[tid] - s2;          // exclusive over pairs
    if (i0 < NBUCK) lstart[i0] = base;
    if (i1 < NBUCK) lstart[i1] = base + a0;
  }
  // one global reservation per non-empty bucket
  for (int i = tid; i < NBUCK; i += 1024)
    cur[i] = (h[i] != 0u) ? atomicAdd(&globcur[i], h[i]) : 0u;
  __syncthreads();

  // place into LDS, bucket-clustered (plain b32 writes; rank from registers)
  #pragma unroll
  for (int j = 0; j < 4; ++j) {
    const int g = tid + j * 1024;
    if (g < ng) {
      #pragma unroll
      for (int q = 0; q < 4; ++q) {
        const int k = j * 4 + q;
        lds[lstart[bu16[k]] + (unsigned)rr[k]] = e[k];
      }
    }
  }
  __syncthreads();

  // flush: wave w -> buckets w, w+16, ...; contiguous LDS -> contiguous global
  const int wid = tid >> 6, lane = tid & 63;
  for (int bu = wid; bu < NBUCK; bu += 16) {
    const unsigned c = h[bu];
    if (c == 0u) continue;                       // wave-uniform branch
    const unsigned gb = cur[bu], lb = lstart[bu];
    for (unsigned s = lane; s < c; s += 64) {
      const unsigned E = lds[lb + s];
      const unsigned g = gb + s;
      if (g < CAPB) {
        sorted[(size_t)bu * CAPB + g] = E;
      } else {
        unsigned o = atomicAdd(ovrcnt, 1u);
        if (o < OVR_CAP) {
          const unsigned pp  = E & 0x3FFFu;
          const unsigned bin = ((unsigned)bu << BBITS) + ((E >> 14) & 31u);
          const float    wf  = (float)(E >> 19) * (1.0f / WQS);
          ovrlist[o] = make_uint2(pp | (bin << 14), __float_as_uint(wf));
        }
      }
    }
  }
}

// ---------- per-bucket spmm: EXACT R8 form (grid = NBUCK, no stealing) --------
// placement (1 atomic + b32/vote) into 32 slabs, then per-bin wave register
// accumulation; uint2 (b64) LDS reads, 2 independent chains.
__global__ __launch_bounds__(512) void k_spmm_static(
    const unsigned* __restrict__ sorted, const unsigned* __restrict__ globcur,
    const float* __restrict__ xT, float* __restrict__ outT,
    unsigned* __restrict__ ovrcnt, uint2* __restrict__ ovrlist) {
  __shared__ unsigned sv[32 * SSTR];       // 24,832 B
  __shared__ unsigned cur[32];
  const int tid = threadIdx.x;
  const int bu = blockIdx.x;
  const int n = min((int)globcur[bu], CAPB);

  if (tid < 32) cur[tid] = 0u;
  __syncthreads();

  // place: 4 votes per 16B load, 1 LDS atomic + 1 b32 write per vote
  const uint4* src = (const uint4*)(sorted + (size_t)bu * CAPB);  // CAPB%4==0
  const int nq = n >> 2;
  #define PLACE(E) { \
    const unsigned fb = ((E) >> 14) & 31u; \
    const unsigned s = atomicAdd(&cur[fb], 1u); \
    if (s < SLAB) sv[fb * SSTR + s] = (E); \
    else { \
      unsigned o = atomicAdd(ovrcnt, 1u); \
      if (o < OVR_CAP) \
        ovrlist[o] = make_uint2(((E) & 0x3FFFu) | ((((unsigned)bu << BBITS) + fb) << 14), \
                                __float_as_uint((float)((E) >> 19) * (1.0f / WQS))); } }
  for (int i = tid; i < nq; i += 512) {
    const uint4 q = src[i];
    PLACE(q.x) PLACE(q.y) PLACE(q.z) PLACE(q.w)
  }
  if (tid < (n & 3)) {                     // tail votes (<=3)
    const unsigned E = sorted[(size_t)bu * CAPB + (n & ~3) + tid];
    PLACE(E)
  }
  #undef PLACE
  __syncthreads();

  // compute: wave wv -> bins [wv*4, wv*4+4); halves take consecutive pairs
  // via ds_read_b64 (SSTR even => 8B aligned); 2 indep chains per iter.
  const int wv = tid >> 6, lane = tid & 63, half = lane >> 5, m = lane & 31;
  #pragma unroll
  for (int s4 = 0; s4 < 4; ++s4) {
    const int b = wv * 4 + s4;
    const int cnt = min((int)cur[b], SLAB);
    const unsigned* seg = &sv[b * SSTR];
    float acc = 0.0f;                      // accumulates wq * x (scaled at end)
    int base = 0;
    for (; base + 8 <= cnt; base += 8) {
      const uint2 a = *(const uint2*)(seg + base + 2 * half);
      const uint2 c = *(const uint2*)(seg + base + 4 + 2 * half);
      acc += (float)(a.x >> 19) * xT[(a.x & 0x3FFFu) * 32 + m];
      acc += (float)(a.y >> 19) * xT[(a.y & 0x3FFFu) * 32 + m];
      acc += (float)(c.x >> 19) * xT[(c.x & 0x3FFFu) * 32 + m];
      acc += (float)(c.y >> 19) * xT[(c.y & 0x3FFFu) * 32 + m];
    }
    for (; base + 4 <= cnt; base += 4) {
      const uint2 a = *(const uint2*)(seg + base + 2 * half);
      acc += (float)(a.x >> 19) * xT[(a.x & 0x3FFFu) * 32 + m];
      acc += (float)(a.y >> 19) * xT[(a.y & 0x3FFFu) * 32 + m];
    }
    if (half == 0) {                       // scalar tail (<=3 votes)
      for (int j = base; j < cnt; ++j) {
        const unsigned E = seg[j];
        acc += (float)(E >> 19) * xT[(E & 0x3FFFu) * 32 + m];
      }
    }
    acc += __shfl_xor(acc, 32);            // combine halves
    if (lane < 32)                         // 128B coalesced store
      outT[(size_t)((bu << BBITS) + b) * 32 + m] = acc * ((1.0f / WQS) * INV_NORM);
  }
}

// ---------- rare overflow votes: direct global atomic into outT ----------------
__global__ __launch_bounds__(1024) void k_overflow(
    const uint2* __restrict__ ovrlist, const unsigned* __restrict__ ovrcnt,
    const float* __restrict__ xT, float* __restrict__ outT) {
  unsigned nz = *ovrcnt;
  unsigned n = nz < (unsigned)OVR_CAP ? nz : (unsigned)OVR_CAP;
  unsigned total = n * 32u;
  for (unsigned i = blockIdx.x * 1024u + threadIdx.x; i < total;
       i += gridDim.x * 1024u) {
    unsigned vi = i >> 5, m = i & 31u;
    uint2 vv = ovrlist[vi];
    unsigned p = vv.x & 0x3FFFu, bin = vv.x >> 14;
    atomicAdd(&outT[(size_t)bin * 32 + m],
              __uint_as_float(vv.y) * xT[p * 32 + m] * INV_NORM);
  }
}

// ---------- outT[33120][32] -> out[32][33120] (LDS tile transpose) ------------
__global__ __launch_bounds__(1024) void k_transpose_out(const float* __restrict__ outT,
                                                        float* __restrict__ out) {
  __shared__ float tile[32][33];
  const int tx = threadIdx.x & 31, ty = threadIdx.x >> 5;
  const int b0 = blockIdx.x * 32;            // NBINS = 1035*32
  tile[ty][tx] = outT[(b0 + ty) * 32 + tx];  // coalesced read
  __syncthreads();
  out[ty * NBINS + b0 + tx] = tile[tx][ty];  // coalesced write, stride-33 LDS
}

// ---------- fallback (ws too small): R1 LDS-histogram version -----------------
__global__ __launch_bounds__(1024) void ht_fallback(const float* __restrict__ x,
                                                    const int* __restrict__ vp,
                                                    const int* __restrict__ vb,
                                                    const float* __restrict__ vw,
                                                    float* __restrict__ out, int nv) {
  __shared__ float hist[NBINS];
  for (int i = threadIdx.x; i < NBINS; i += 1024) hist[i] = 0.0f;
  __syncthreads();
  const int map = blockIdx.x >> 3, chunk = blockIdx.x & 7;
  const float* xm = x + map * IM_HW;
  const int per = (nv + 7) / 8;
  const int start = chunk * per, end = min(nv, start + per);
  for (int i = start + (int)threadIdx.x; i < end; i += 1024)
    atomicAdd(&hist[vb[i]], xm[vp[i]] * vw[i]);
  __syncthreads();
  float* om = out + map * NBINS;
  for (int i = threadIdx.x; i < NBINS; i += 1024)
    atomicAdd(&om[i], hist[i] * INV_NORM);
}

extern "C" void kernel_launch(void* const* d_in, const int* in_sizes, int n_in,
                              void* d_out, int out_size, void* d_ws, size_t ws_size,
                              hipStream_t stream) {
  const float* x  = (const float*)d_in[0];
  const int*   vp = (const int*)d_in[1];
  const int*   vb = (const int*)d_in[2];
  const float* vw = (const float*)d_in[3];
  float* out = (float*)d_out;
  const int nv = in_sizes[1];

  // ws layout (all sections 16B-aligned)
  char* w = (char*)d_ws;
  unsigned* sorted  = (unsigned*)w; w += (size_t)NBUCK * CAPB * 4;   // 18.0 MB
  float*    xT      = (float*)w;    w += (size_t)IM_HW * NMAPS * 4;  // 2 MB
  float*    outT    = (float*)w;    w += (size_t)NBINS * NMAPS * 4;  // 4.2 MB
  uint2*    ovrlist = (uint2*)w;    w += (size_t)OVR_CAP * 8;        // 64 KB
  unsigned* globcur = (unsigned*)w; w += (size_t)NBUCK * 4;          // 4140 B
  unsigned* ovrcnt  = (unsigned*)w; w += 16;                         // pad to 16
  const size_t need = (size_t)(w - (char*)d_ws);

  if (ws_size >= need) {
    // zero globcur + ovrcnt (one contiguous region)
    hipMemsetAsync(globcur, 0, (size_t)NBUCK * 4 + 16, stream);
    k_scatter_bucket<<<NB_SCAT, 1024, 0, stream>>>(x, xT, vp, vb, vw, nv, globcur,
                                                   ovrcnt, ovrlist, sorted);
    k_spmm_static<<<NBUCK, 512, 0, stream>>>(sorted, globcur, xT, outT,
                                             ovrcnt, ovrlist);
    k_overflow<<<8, 1024, 0, stream>>>(ovrlist, ovrcnt, xT, outT);
    k_transpose_out<<<NBINS / 32, 1024, 0, stream>>>(outT, out);
  } else {
    hipMemsetAsync(out, 0, (size_t)out_size * sizeof(float), stream);
    ht_fallback<<<256, 1024, 0, stream>>>(x, vp, vb, vw, out, nv);
  }
}

// Round 12
// 157.622 us; speedup vs baseline: 1.3093x; 1.0223x over previous
//
#include <hip/hip_runtime.h>
#include <stdint.h>

// Problem constants
#define IM_HW   16384            // 128*128 pixels
#define NBINS   33120            // 184*180
#define NMAPS   32               // b*c = 2*16
#define INV_NORM (1.0f / 128.0f)

#define BBITS   5                // bins per bucket = 32
#define NBUCK   1035             // NBINS/32 exactly
#define CAPB    4352             // slots/bucket (mean 3865, +7.8 sigma), %4==0
#define SLAB    192              // LDS slots per fine bin (mean 120.8, +6.5 sigma)
#define SSTR    194              // slab stride (even: b64-aligned; ≡2 mod 32: bank spread)
#define NB_SCAT 256              // scatter blocks
#define OVR_CAP 8192             // overflow list capacity (votes)
#define WQS     8191.0f          // 13-bit weight quantization scale

// ---------- bucket scatter (R8-proven) + fused xT transpose prologue ----------
__global__ __launch_bounds__(1024) void k_scatter_bucket(
    const float* __restrict__ x, float* __restrict__ xT,
    const int* __restrict__ vp, const int* __restrict__ vb,
    const float* __restrict__ vw, int nv,
    unsigned* __restrict__ globcur,      // [NBUCK] bucket fills (pre-zeroed)
    unsigned* __restrict__ ovrcnt,       // [1] overflow count (pre-zeroed)
    uint2*   __restrict__ ovrlist,       // [OVR_CAP]
    unsigned* __restrict__ sorted) {     // [NBUCK*CAPB] 4B entries
  __shared__ unsigned h[NBUCK];          // per-bucket counts
  __shared__ unsigned lstart[NBUCK];     // local exclusive starts
  __shared__ unsigned cur[NBUCK];        // global reserved bases
  __shared__ unsigned sc[1024];          // scan temp
  __shared__ unsigned lds[16384];        // block-local bucket-sorted votes (64KB)

  const int tid = threadIdx.x;

  // fused transpose: x[32][16384] -> xT[16384][32] (write-coalesced)
  {
    const int base = blockIdx.x * 2048;          // 256*2048 = 524288 = 32*16384
    #pragma unroll
    for (int k = 0; k < 2; ++k) {
      const int i = base + k * 1024 + tid;       // i = p*32 + m
      const int m = i & 31, p = i >> 5;
      xT[i] = x[m * IM_HW + p];
    }
  }

  const int chunk = (((nv + NB_SCAT - 1) / NB_SCAT) + 3) & ~3;   // 4-aligned
  const int c0 = blockIdx.x * chunk;
  const int c1 = min(nv, c0 + chunk);
  const int cnt = (c1 > c0) ? (c1 - c0) : 0;    // <= 15628 <= 16384

  for (int i = tid; i < NBUCK; i += 1024) h[i] = 0u;
  __syncthreads();

  // stage + rank (1 LDS atomic per vote; return value = within-bucket rank)
  unsigned e[16];
  unsigned short rr[16], bu16[16];
  const int ng = cnt >> 2;                       // groups of 4 votes
  const int4*   vp4 = (const int4*)(vp + c0);
  const int4*   vb4 = (const int4*)(vb + c0);
  const float4* vw4 = (const float4*)(vw + c0);
  #pragma unroll
  for (int j = 0; j < 4; ++j) {
    const int g = tid + j * 1024;
    if (g < ng) {
      const int4 p = vp4[g]; const int4 b = vb4[g]; const float4 w = vw4[g];
      const int k = j * 4;
      #define STAGE(q, PP, BB, WW) { \
        const unsigned wq = (unsigned)((WW) * WQS + 0.5f); \
        e[k + q] = (unsigned)(PP) | (((unsigned)(BB) & 31u) << 14) | (wq << 19); \
        bu16[k + q] = (unsigned short)((unsigned)(BB) >> BBITS); \
        rr[k + q] = (unsigned short)atomicAdd(&h[(unsigned)(BB) >> BBITS], 1u); }
      STAGE(0, p.x, b.x, w.x) STAGE(1, p.y, b.y, w.y)
      STAGE(2, p.z, b.z, w.z) STAGE(3, p.w, b.w, w.w)
      #undef STAGE
    }
  }
  // robustness tail (cnt%4, zero for nv=4M): straight to overflow list
  const int tail0 = ng * 4;
  if (tid < cnt - tail0) {
    const int gi = c0 + tail0 + tid;
    unsigned o = atomicAdd(ovrcnt, 1u);
    if (o < OVR_CAP)
      ovrlist[o] = make_uint2((unsigned)vp[gi] | ((unsigned)vb[gi] << 14),
                              __float_as_uint(vw[gi]));
  }
  __syncthreads();

  // block-local exclusive scan of h -> lstart (2 buckets/thread, HS-1024)
  {
    const int i0 = 2 * tid, i1 = 2 * tid + 1;
    const unsigned a0 = (i0 < NBUCK) ? h[i0] : 0u;
    const unsigned a1 = (i1 < NBUCK) ? h[i1] : 0u;
    const unsigned s2 = a0 + a1;
    sc[tid] = s2;
    __syncthreads();
    for (int d = 1; d < 1024; d <<= 1) {
      const unsigned v = (tid >= d) ? sc[tid - d] : 0u;
      __syncthreads();
      sc[tid] += v;
      __syncthreads();
    }
    const unsigned base = sc[tid] - s2;          // exclusive over pairs
    if (i0 < NBUCK) lstart[i0] = base;
    if (i1 < NBUCK) lstart[i1] = base + a0;
  }
  // one global reservation per non-empty bucket
  for (int i = tid; i < NBUCK; i += 1024)
    cur[i] = (h[i] != 0u) ? atomicAdd(&globcur[i], h[i]) : 0u;
  __syncthreads();

  // place into LDS, bucket-clustered (plain b32 writes; rank from registers)
  #pragma unroll
  for (int j = 0; j < 4; ++j) {
    const int g = tid + j * 1024;
    if (g < ng) {
      #pragma unroll
      for (int q = 0; q < 4; ++q) {
        const int k = j * 4 + q;
        lds[lstart[bu16[k]] + (unsigned)rr[k]] = e[k];
      }
    }
  }
  __syncthreads();

  // flush: wave w -> buckets w, w+16, ...; contiguous LDS -> contiguous global
  const int wid = tid >> 6, lane = tid & 63;
  for (int bu = wid; bu < NBUCK; bu += 16) {
    const unsigned c = h[bu];
    if (c == 0u) continue;                       // wave-uniform branch
    const unsigned gb = cur[bu], lb = lstart[bu];
    for (unsigned s = lane; s < c; s += 64) {
      const unsigned E = lds[lb + s];
      const unsigned g = gb + s;
      if (g < CAPB) {
        sorted[(size_t)bu * CAPB + g] = E;
      } else {
        unsigned o = atomicAdd(ovrcnt, 1u);
        if (o < OVR_CAP) {
          const unsigned pp  = E & 0x3FFFu;
          const unsigned bin = ((unsigned)bu << BBITS) + ((E >> 14) & 31u);
          const float    wf  = (float)(E >> 19) * (1.0f / WQS);
          ovrlist[o] = make_uint2(pp | (bin << 14), __float_as_uint(wf));
        }
      }
    }
  }
}

// ---------- per-bucket spmm (R8-proven body) + fused transposed epilogue ------
// placement (1 atomic + b32/vote) into 32 slabs, per-bin wave register accum,
// then 32x33 LDS tile -> direct coalesced write of out[m][bin_base..+32).
__global__ __launch_bounds__(512) void k_spmm_static(
    const unsigned* __restrict__ sorted, const unsigned* __restrict__ globcur,
    const float* __restrict__ xT, float* __restrict__ out,
    unsigned* __restrict__ ovrcnt, uint2* __restrict__ ovrlist) {
  __shared__ unsigned sv[32 * SSTR];       // 24,832 B
  __shared__ unsigned cur[32];
  __shared__ float tile[32][33];           // [bin][map], +1 pad
  const int tid = threadIdx.x;
  const int bu = blockIdx.x;
  const int n = min((int)globcur[bu], CAPB);

  if (tid < 32) cur[tid] = 0u;
  __syncthreads();

  // place: 4 votes per 16B load, 1 LDS atomic + 1 b32 write per vote
  const uint4* src = (const uint4*)(sorted + (size_t)bu * CAPB);  // CAPB%4==0
  const int nq = n >> 2;
  #define PLACE(E) { \
    const unsigned fb = ((E) >> 14) & 31u; \
    const unsigned s = atomicAdd(&cur[fb], 1u); \
    if (s < SLAB) sv[fb * SSTR + s] = (E); \
    else { \
      unsigned o = atomicAdd(ovrcnt, 1u); \
      if (o < OVR_CAP) \
        ovrlist[o] = make_uint2(((E) & 0x3FFFu) | ((((unsigned)bu << BBITS) + fb) << 14), \
                                __float_as_uint((float)((E) >> 19) * (1.0f / WQS))); } }
  for (int i = tid; i < nq; i += 512) {
    const uint4 q = src[i];
    PLACE(q.x) PLACE(q.y) PLACE(q.z) PLACE(q.w)
  }
  if (tid < (n & 3)) {                     // tail votes (<=3)
    const unsigned E = sorted[(size_t)bu * CAPB + (n & ~3) + tid];
    PLACE(E)
  }
  #undef PLACE
  __syncthreads();

  // compute: wave wv -> bins [wv*4, wv*4+4); halves take consecutive pairs
  // via ds_read_b64 (SSTR even => 8B aligned); 2 indep chains per iter.
  const int wv = tid >> 6, lane = tid & 63, half = lane >> 5, m = lane & 31;
  #pragma unroll
  for (int s4 = 0; s4 < 4; ++s4) {
    const int b = wv * 4 + s4;
    const int cnt = min((int)cur[b], SLAB);
    const unsigned* seg = &sv[b * SSTR];
    float acc = 0.0f;                      // accumulates wq * x (scaled at end)
    int base = 0;
    for (; base + 8 <= cnt; base += 8) {
      const uint2 a = *(const uint2*)(seg + base + 2 * half);
      const uint2 c = *(const uint2*)(seg + base + 4 + 2 * half);
      acc += (float)(a.x >> 19) * xT[(a.x & 0x3FFFu) * 32 + m];
      acc += (float)(a.y >> 19) * xT[(a.y & 0x3FFFu) * 32 + m];
      acc += (float)(c.x >> 19) * xT[(c.x & 0x3FFFu) * 32 + m];
      acc += (float)(c.y >> 19) * xT[(c.y & 0x3FFFu) * 32 + m];
    }
    for (; base + 4 <= cnt; base += 4) {
      const uint2 a = *(const uint2*)(seg + base + 2 * half);
      acc += (float)(a.x >> 19) * xT[(a.x & 0x3FFFu) * 32 + m];
      acc += (float)(a.y >> 19) * xT[(a.y & 0x3FFFu) * 32 + m];
    }
    if (half == 0) {                       // scalar tail (<=3 votes)
      for (int j = base; j < cnt; ++j) {
        const unsigned E = seg[j];
        acc += (float)(E >> 19) * xT[(E & 0x3FFFu) * 32 + m];
      }
    }
    acc += __shfl_xor(acc, 32);            // combine halves
    if (lane < 32)                         // stage result in tile
      tile[b][m] = acc * ((1.0f / WQS) * INV_NORM);
  }
  __syncthreads();

  // fused transposed write: out[m][bin_base + c] for c in [0,32).
  // thread -> (row m = tid>>4, 2 cols); 128B contiguous per row, coalesced.
  {
    const int row  = tid >> 4;             // 0..31 (map index)
    const int col2 = (tid & 15) * 2;       // 0,2,..,30 (bin offset)
    const int gb0  = bu << BBITS;
    const float2 v2 = make_float2(tile[col2][row], tile[col2 + 1][row]);
    *(float2*)(out + (size_t)row * NBINS + gb0 + col2) = v2;
  }
}

// ---------- rare overflow votes: direct global atomic into out (transposed) ---
__global__ __launch_bounds__(1024) void k_overflow(
    const uint2* __restrict__ ovrlist, const unsigned* __restrict__ ovrcnt,
    const float* __restrict__ xT, float* __restrict__ out) {
  unsigned nz = *ovrcnt;
  unsigned n = nz < (unsigned)OVR_CAP ? nz : (unsigned)OVR_CAP;
  unsigned total = n * 32u;
  for (unsigned i = blockIdx.x * 1024u + threadIdx.x; i < total;
       i += gridDim.x * 1024u) {
    unsigned vi = i >> 5, m = i & 31u;
    uint2 vv = ovrlist[vi];
    unsigned p = vv.x & 0x3FFFu, bin = vv.x >> 14;
    atomicAdd(&out[(size_t)m * NBINS + bin],
              __uint_as_float(vv.y) * xT[p * 32 + m] * INV_NORM);
  }
}

// ---------- fallback (ws too small): R1 LDS-histogram version -----------------
__global__ __launch_bounds__(1024) void ht_fallback(const float* __restrict__ x,
                                                    const int* __restrict__ vp,
                                                    const int* __restrict__ vb,
                                                    const float* __restrict__ vw,
                                                    float* __restrict__ out, int nv) {
  __shared__ float hist[NBINS];
  for (int i = threadIdx.x; i < NBINS; i += 1024) hist[i] = 0.0f;
  __syncthreads();
  const int map = blockIdx.x >> 3, chunk = blockIdx.x & 7;
  const float* xm = x + map * IM_HW;
  const int per = (nv + 7) / 8;
  const int start = chunk * per, end = min(nv, start + per);
  for (int i = start + (int)threadIdx.x; i < end; i += 1024)
    atomicAdd(&hist[vb[i]], xm[vp[i]] * vw[i]);
  __syncthreads();
  float* om = out + map * NBINS;
  for (int i = threadIdx.x; i < NBINS; i += 1024)
    atomicAdd(&om[i], hist[i] * INV_NORM);
}

extern "C" void kernel_launch(void* const* d_in, const int* in_sizes, int n_in,
                              void* d_out, int out_size, void* d_ws, size_t ws_size,
                              hipStream_t stream) {
  const float* x  = (const float*)d_in[0];
  const int*   vp = (const int*)d_in[1];
  const int*   vb = (const int*)d_in[2];
  const float* vw = (const float*)d_in[3];
  float* out = (float*)d_out;
  const int nv = in_sizes[1];

  // ws layout (all sections 16B-aligned)
  char* w = (char*)d_ws;
  unsigned* sorted  = (unsigned*)w; w += (size_t)NBUCK * CAPB * 4;   // 18.0 MB
  float*    xT      = (float*)w;    w += (size_t)IM_HW * NMAPS * 4;  // 2 MB
  uint2*    ovrlist = (uint2*)w;    w += (size_t)OVR_CAP * 8;        // 64 KB
  unsigned* globcur = (unsigned*)w; w += (size_t)NBUCK * 4;          // 4140 B
  unsigned* ovrcnt  = (unsigned*)w; w += 16;                         // pad to 16
  const size_t need = (size_t)(w - (char*)d_ws);

  if (ws_size >= need) {
    // zero globcur + ovrcnt (one contiguous region)
    hipMemsetAsync(globcur, 0, (size_t)NBUCK * 4 + 16, stream);
    k_scatter_bucket<<<NB_SCAT, 1024, 0, stream>>>(x, xT, vp, vb, vw, nv, globcur,
                                                   ovrcnt, ovrlist, sorted);
    k_spmm_static<<<NBUCK, 512, 0, stream>>>(sorted, globcur, xT, out,
                                             ovrcnt, ovrlist);
    k_overflow<<<8, 1024, 0, stream>>>(ovrlist, ovrcnt, xT, out);
  } else {
    hipMemsetAsync(out, 0, (size_t)out_size * sizeof(float), stream);
    ht_fallback<<<256, 1024, 0, stream>>>(x, vp, vb, vw, out, nv);
  }
}

// Round 13
// 156.941 us; speedup vs baseline: 1.3150x; 1.0043x over previous
//
#include <hip/hip_runtime.h>
#include <stdint.h>

// Problem constants
#define IM_HW   16384            // 128*128 pixels
#define NBINS   33120            // 184*180
#define NMAPS   32               // b*c = 2*16
#define INV_NORM (1.0f / 128.0f)

#define BBITS   5                // bins per bucket = 32
#define NBUCK   1035             // NBINS/32 exactly
#define CAPB    4352             // slots/bucket (mean 3865, +7.8 sigma), %4==0
#define SLAB    192              // LDS slots per fine bin (mean 120.8, +6.5 sigma)
#define SSTR    194              // slab stride (even: b64-aligned; ≡2 mod 32: bank spread)
#define NB_SCAT 256              // scatter blocks
#define OVR_CAP 8192             // overflow list capacity (votes)

// Weight encoding: top-13 bits of the f16 bit pattern, stored at [19,32).
// Slab entries clear fb ([14,19)) so bits [16,32) form a valid (3-LSB-zeroed)
// f16 directly usable by v_cvt_f32_f16/fma_mix without shifts.
__device__ __forceinline__ float w_from_top13(unsigned e) {   // e>>19 = top13
  const unsigned short hb = (unsigned short)((e >> 19) << 3);
  return (float)__builtin_bit_cast(_Float16, hb);
}

// ---------- bucket scatter (R8-proven) + fused xT transpose prologue ----------
__global__ __launch_bounds__(1024) void k_scatter_bucket(
    const float* __restrict__ x, float* __restrict__ xT,
    const int* __restrict__ vp, const int* __restrict__ vb,
    const float* __restrict__ vw, int nv,
    unsigned* __restrict__ globcur,      // [NBUCK] bucket fills (pre-zeroed)
    unsigned* __restrict__ ovrcnt,       // [1] overflow count (pre-zeroed)
    uint2*   __restrict__ ovrlist,       // [OVR_CAP]
    unsigned* __restrict__ sorted) {     // [NBUCK*CAPB] 4B entries
  __shared__ unsigned h[NBUCK];          // per-bucket counts
  __shared__ unsigned lstart[NBUCK];     // local exclusive starts
  __shared__ unsigned cur[NBUCK];        // global reserved bases
  __shared__ unsigned sc[1024];          // scan temp
  __shared__ unsigned lds[16384];        // block-local bucket-sorted votes (64KB)

  const int tid = threadIdx.x;

  // fused transpose: x[32][16384] -> xT[16384][32] (write-coalesced)
  {
    const int base = blockIdx.x * 2048;          // 256*2048 = 524288 = 32*16384
    #pragma unroll
    for (int k = 0; k < 2; ++k) {
      const int i = base + k * 1024 + tid;       // i = p*32 + m
      const int m = i & 31, p = i >> 5;
      xT[i] = x[m * IM_HW + p];
    }
  }

  const int chunk = (((nv + NB_SCAT - 1) / NB_SCAT) + 3) & ~3;   // 4-aligned
  const int c0 = blockIdx.x * chunk;
  const int c1 = min(nv, c0 + chunk);
  const int cnt = (c1 > c0) ? (c1 - c0) : 0;    // <= 15628 <= 16384

  for (int i = tid; i < NBUCK; i += 1024) h[i] = 0u;
  __syncthreads();

  // stage + rank (1 LDS atomic per vote; return value = within-bucket rank)
  unsigned e[16];
  unsigned short rr[16], bu16[16];
  const int ng = cnt >> 2;                       // groups of 4 votes
  const int4*   vp4 = (const int4*)(vp + c0);
  const int4*   vb4 = (const int4*)(vb + c0);
  const float4* vw4 = (const float4*)(vw + c0);
  #pragma unroll
  for (int j = 0; j < 4; ++j) {
    const int g = tid + j * 1024;
    if (g < ng) {
      const int4 p = vp4[g]; const int4 b = vb4[g]; const float4 w = vw4[g];
      const int k = j * 4;
      #define STAGE(q, PP, BB, WW) { \
        const unsigned short hw = __builtin_bit_cast(unsigned short, (_Float16)(WW)); \
        e[k + q] = (unsigned)(PP) | (((unsigned)(BB) & 31u) << 14) | (((unsigned)hw >> 3) << 19); \
        bu16[k + q] = (unsigned short)((unsigned)(BB) >> BBITS); \
        rr[k + q] = (unsigned short)atomicAdd(&h[(unsigned)(BB) >> BBITS], 1u); }
      STAGE(0, p.x, b.x, w.x) STAGE(1, p.y, b.y, w.y)
      STAGE(2, p.z, b.z, w.z) STAGE(3, p.w, b.w, w.w)
      #undef STAGE
    }
  }
  // robustness tail (cnt%4, zero for nv=4M): straight to overflow list
  const int tail0 = ng * 4;
  if (tid < cnt - tail0) {
    const int gi = c0 + tail0 + tid;
    unsigned o = atomicAdd(ovrcnt, 1u);
    if (o < OVR_CAP)
      ovrlist[o] = make_uint2((unsigned)vp[gi] | ((unsigned)vb[gi] << 14),
                              __float_as_uint(vw[gi]));
  }
  __syncthreads();

  // block-local exclusive scan of h -> lstart (2 buckets/thread, HS-1024)
  {
    const int i0 = 2 * tid, i1 = 2 * tid + 1;
    const unsigned a0 = (i0 < NBUCK) ? h[i0] : 0u;
    const unsigned a1 = (i1 < NBUCK) ? h[i1] : 0u;
    const unsigned s2 = a0 + a1;
    sc[tid] = s2;
    __syncthreads();
    for (int d = 1; d < 1024; d <<= 1) {
      const unsigned v = (tid >= d) ? sc[tid - d] : 0u;
      __syncthreads();
      sc[tid] += v;
      __syncthreads();
    }
    const unsigned base = sc[tid] - s2;          // exclusive over pairs
    if (i0 < NBUCK) lstart[i0] = base;
    if (i1 < NBUCK) lstart[i1] = base + a0;
  }
  // one global reservation per non-empty bucket
  for (int i = tid; i < NBUCK; i += 1024)
    cur[i] = (h[i] != 0u) ? atomicAdd(&globcur[i], h[i]) : 0u;
  __syncthreads();

  // place into LDS, bucket-clustered (plain b32 writes; rank from registers)
  #pragma unroll
  for (int j = 0; j < 4; ++j) {
    const int g = tid + j * 1024;
    if (g < ng) {
      #pragma unroll
      for (int q = 0; q < 4; ++q) {
        const int k = j * 4 + q;
        lds[lstart[bu16[k]] + (unsigned)rr[k]] = e[k];
      }
    }
  }
  __syncthreads();

  // flush: wave w -> buckets w, w+16, ...; contiguous LDS -> contiguous global
  const int wid = tid >> 6, lane = tid & 63;
  for (int bu = wid; bu < NBUCK; bu += 16) {
    const unsigned c = h[bu];
    if (c == 0u) continue;                       // wave-uniform branch
    const unsigned gb = cur[bu], lb = lstart[bu];
    for (unsigned s = lane; s < c; s += 64) {
      const unsigned E = lds[lb + s];
      const unsigned g = gb + s;
      if (g < CAPB) {
        sorted[(size_t)bu * CAPB + g] = E;
      } else {
        unsigned o = atomicAdd(ovrcnt, 1u);
        if (o < OVR_CAP) {
          const unsigned pp  = E & 0x3FFFu;
          const unsigned bin = ((unsigned)bu << BBITS) + ((E >> 14) & 31u);
          ovrlist[o] = make_uint2(pp | (bin << 14), __float_as_uint(w_from_top13(E)));
        }
      }
    }
  }
}

// ---------- per-bucket spmm (R8-proven body) + fused transposed epilogue ------
// placement strips fb with one AND (bits [16,32) become a valid f16 weight);
// compute loop: and + lshl_add + load + f16-fma per vote (no shr/cvt-u32).
__global__ __launch_bounds__(512) void k_spmm_static(
    const unsigned* __restrict__ sorted, const unsigned* __restrict__ globcur,
    const float* __restrict__ xT, float* __restrict__ out,
    unsigned* __restrict__ ovrcnt, uint2* __restrict__ ovrlist) {
  __shared__ unsigned sv[32 * SSTR];       // 24,832 B
  __shared__ unsigned cur[32];
  __shared__ float tile[32][33];           // [bin][map], +1 pad
  const int tid = threadIdx.x;
  const int bu = blockIdx.x;
  const int n = min((int)globcur[bu], CAPB);

  if (tid < 32) cur[tid] = 0u;
  __syncthreads();

  // place: 4 votes per 16B load, 1 LDS atomic + 1 b32 write per vote
  const uint4* src = (const uint4*)(sorted + (size_t)bu * CAPB);  // CAPB%4==0
  const int nq = n >> 2;
  #define PLACE(E) { \
    const unsigned fb = ((E) >> 14) & 31u; \
    const unsigned s = atomicAdd(&cur[fb], 1u); \
    if (s < SLAB) sv[fb * SSTR + s] = (E) & 0xFFF83FFFu; \
    else { \
      unsigned o = atomicAdd(ovrcnt, 1u); \
      if (o < OVR_CAP) \
        ovrlist[o] = make_uint2(((E) & 0x3FFFu) | ((((unsigned)bu << BBITS) + fb) << 14), \
                                __float_as_uint(w_from_top13(E))); } }
  for (int i = tid; i < nq; i += 512) {
    const uint4 q = src[i];
    PLACE(q.x) PLACE(q.y) PLACE(q.z) PLACE(q.w)
  }
  if (tid < (n & 3)) {                     // tail votes (<=3)
    const unsigned E = sorted[(size_t)bu * CAPB + (n & ~3) + tid];
    PLACE(E)
  }
  #undef PLACE
  __syncthreads();

  // compute: wave wv -> bins [wv*4, wv*4+4); halves take consecutive pairs
  // via ds_read_b64 (SSTR even => 8B aligned); 2 indep chains per iter.
  // Weight = f16 in entry bits [16,32): (float)bitcast<f16>(E>>16).
  #define WDEC(E) ((float)__builtin_bit_cast(_Float16, (unsigned short)((E) >> 16)))
  const int wv = tid >> 6, lane = tid & 63, half = lane >> 5, m = lane & 31;
  #pragma unroll
  for (int s4 = 0; s4 < 4; ++s4) {
    const int b = wv * 4 + s4;
    const int cnt = min((int)cur[b], SLAB);
    const unsigned* seg = &sv[b * SSTR];
    float acc = 0.0f;
    int base = 0;
    for (; base + 8 <= cnt; base += 8) {
      const uint2 a = *(const uint2*)(seg + base + 2 * half);
      const uint2 c = *(const uint2*)(seg + base + 4 + 2 * half);
      acc += WDEC(a.x) * xT[(a.x & 0x3FFFu) * 32 + m];
      acc += WDEC(a.y) * xT[(a.y & 0x3FFFu) * 32 + m];
      acc += WDEC(c.x) * xT[(c.x & 0x3FFFu) * 32 + m];
      acc += WDEC(c.y) * xT[(c.y & 0x3FFFu) * 32 + m];
    }
    for (; base + 4 <= cnt; base += 4) {
      const uint2 a = *(const uint2*)(seg + base + 2 * half);
      acc += WDEC(a.x) * xT[(a.x & 0x3FFFu) * 32 + m];
      acc += WDEC(a.y) * xT[(a.y & 0x3FFFu) * 32 + m];
    }
    if (half == 0) {                       // scalar tail (<=3 votes)
      for (int j = base; j < cnt; ++j) {
        const unsigned E = seg[j];
        acc += WDEC(E) * xT[(E & 0x3FFFu) * 32 + m];
      }
    }
    acc += __shfl_xor(acc, 32);            // combine halves
    if (lane < 32)                         // stage result in tile
      tile[b][m] = acc * INV_NORM;
  }
  #undef WDEC
  __syncthreads();

  // fused transposed write: out[m][bin_base + c] for c in [0,32).
  {
    const int row  = tid >> 4;             // 0..31 (map index)
    const int col2 = (tid & 15) * 2;       // 0,2,..,30 (bin offset)
    const int gb0  = bu << BBITS;
    const float2 v2 = make_float2(tile[col2][row], tile[col2 + 1][row]);
    *(float2*)(out + (size_t)row * NBINS + gb0 + col2) = v2;
  }
}

// ---------- rare overflow votes: direct global atomic into out (transposed) ---
__global__ __launch_bounds__(1024) void k_overflow(
    const uint2* __restrict__ ovrlist, const unsigned* __restrict__ ovrcnt,
    const float* __restrict__ xT, float* __restrict__ out) {
  unsigned nz = *ovrcnt;
  unsigned n = nz < (unsigned)OVR_CAP ? nz : (unsigned)OVR_CAP;
  unsigned total = n * 32u;
  for (unsigned i = blockIdx.x * 1024u + threadIdx.x; i < total;
       i += gridDim.x * 1024u) {
    unsigned vi = i >> 5, m = i & 31u;
    uint2 vv = ovrlist[vi];
    unsigned p = vv.x & 0x3FFFu, bin = vv.x >> 14;
    atomicAdd(&out[(size_t)m * NBINS + bin],
              __uint_as_float(vv.y) * xT[p * 32 + m] * INV_NORM);
  }
}

// ---------- fallback (ws too small): R1 LDS-histogram version -----------------
__global__ __launch_bounds__(1024) void ht_fallback(const float* __restrict__ x,
                                                    const int* __restrict__ vp,
                                                    const int* __restrict__ vb,
                                                    const float* __restrict__ vw,
                                                    float* __restrict__ out, int nv) {
  __shared__ float hist[NBINS];
  for (int i = threadIdx.x; i < NBINS; i += 1024) hist[i] = 0.0f;
  __syncthreads();
  const int map = blockIdx.x >> 3, chunk = blockIdx.x & 7;
  const float* xm = x + map * IM_HW;
  const int per = (nv + 7) / 8;
  const int start = chunk * per, end = min(nv, start + per);
  for (int i = start + (int)threadIdx.x; i < end; i += 1024)
    atomicAdd(&hist[vb[i]], xm[vp[i]] * vw[i]);
  __syncthreads();
  float* om = out + map * NBINS;
  for (int i = threadIdx.x; i < NBINS; i += 1024)
    atomicAdd(&om[i], hist[i] * INV_NORM);
}

extern "C" void kernel_launch(void* const* d_in, const int* in_sizes, int n_in,
                              void* d_out, int out_size, void* d_ws, size_t ws_size,
                              hipStream_t stream) {
  const float* x  = (const float*)d_in[0];
  const int*   vp = (const int*)d_in[1];
  const int*   vb = (const int*)d_in[2];
  const float* vw = (const float*)d_in[3];
  float* out = (float*)d_out;
  const int nv = in_sizes[1];

  // ws layout (all sections 16B-aligned)
  char* w = (char*)d_ws;
  unsigned* sorted  = (unsigned*)w; w += (size_t)NBUCK * CAPB * 4;   // 18.0 MB
  float*    xT      = (float*)w;    w += (size_t)IM_HW * NMAPS * 4;  // 2 MB
  uint2*    ovrlist = (uint2*)w;    w += (size_t)OVR_CAP * 8;        // 64 KB
  unsigned* globcur = (unsigned*)w; w += (size_t)NBUCK * 4;          // 4140 B
  unsigned* ovrcnt  = (unsigned*)w; w += 16;                         // pad to 16
  const size_t need = (size_t)(w - (char*)d_ws);

  if (ws_size >= need) {
    // zero globcur + ovrcnt (one contiguous region)
    hipMemsetAsync(globcur, 0, (size_t)NBUCK * 4 + 16, stream);
    k_scatter_bucket<<<NB_SCAT, 1024, 0, stream>>>(x, xT, vp, vb, vw, nv, globcur,
                                                   ovrcnt, ovrlist, sorted);
    k_spmm_static<<<NBUCK, 512, 0, stream>>>(sorted, globcur, xT, out,
                                             ovrcnt, ovrlist);
    k_overflow<<<8, 1024, 0, stream>>>(ovrlist, ovrcnt, xT, out);
  } else {
    hipMemsetAsync(out, 0, (size_t)out_size * sizeof(float), stream);
    ht_fallback<<<256, 1024, 0, stream>>>(x, vp, vb, vw, out, nv);
  }
}

// Round 14
// 154.852 us; speedup vs baseline: 1.3327x; 1.0135x over previous
//
#include <hip/hip_runtime.h>
#include <stdint.h>

// Problem constants
#define IM_HW   16384            // 128*128 pixels
#define NBINS   33120            // 184*180
#define NMAPS   32               // b*c = 2*16
#define INV_NORM (1.0f / 128.0f)

#define BBITS   5                // bins per bucket = 32
#define NBUCK   1035             // NBINS/32 exactly
#define CAPB    4352             // slots/bucket (mean 3865, +7.8 sigma), %4==0
#define SLAB    192              // LDS slots per fine bin (mean 120.8, +6.5 sigma)
#define SSTR    194              // slab stride (even: b64-aligned; ≡2 mod 32: bank spread)
#define NB_SCAT 256              // scatter blocks
#define OVR_CAP 8192             // overflow list capacity (votes)

// Weight encoding: top-13 bits of the f16 bit pattern, stored at [19,32).
__device__ __forceinline__ float w_from_top13(unsigned e) {   // e>>19 = top13
  const unsigned short hb = (unsigned short)((e >> 19) << 3);
  return (float)__builtin_bit_cast(_Float16, hb);
}

// ---------- bucket scatter (R8-proven) + fused xT transpose prologue ----------
// Scan replaced by single-wave shfl scan (saves ~18 block barriers).
__global__ __launch_bounds__(1024) void k_scatter_bucket(
    const float* __restrict__ x, float* __restrict__ xT,
    const int* __restrict__ vp, const int* __restrict__ vb,
    const float* __restrict__ vw, int nv,
    unsigned* __restrict__ globcur,      // [NBUCK] bucket fills (pre-zeroed)
    unsigned* __restrict__ ovrcnt,       // [1] overflow count (pre-zeroed)
    uint2*   __restrict__ ovrlist,       // [OVR_CAP]
    unsigned* __restrict__ sorted) {     // [NBUCK*CAPB] 4B entries
  __shared__ unsigned h[NBUCK];          // per-bucket counts
  __shared__ unsigned lstart[NBUCK];     // local exclusive starts
  __shared__ unsigned cur[NBUCK];        // global reserved bases
  __shared__ unsigned lds[16384];        // block-local bucket-sorted votes (64KB)

  const int tid = threadIdx.x;

  // fused transpose: x[32][16384] -> xT[16384][32] (write-coalesced)
  {
    const int base = blockIdx.x * 2048;          // 256*2048 = 524288 = 32*16384
    #pragma unroll
    for (int k = 0; k < 2; ++k) {
      const int i = base + k * 1024 + tid;       // i = p*32 + m
      const int m = i & 31, p = i >> 5;
      xT[i] = x[m * IM_HW + p];
    }
  }

  const int chunk = (((nv + NB_SCAT - 1) / NB_SCAT) + 3) & ~3;   // 4-aligned
  const int c0 = blockIdx.x * chunk;
  const int c1 = min(nv, c0 + chunk);
  const int cnt = (c1 > c0) ? (c1 - c0) : 0;    // <= 15628 <= 16384

  for (int i = tid; i < NBUCK; i += 1024) h[i] = 0u;
  __syncthreads();

  // stage + rank (1 LDS atomic per vote; return value = within-bucket rank)
  unsigned e[16];
  unsigned short rr[16], bu16[16];
  const int ng = cnt >> 2;                       // groups of 4 votes
  const int4*   vp4 = (const int4*)(vp + c0);
  const int4*   vb4 = (const int4*)(vb + c0);
  const float4* vw4 = (const float4*)(vw + c0);
  #pragma unroll
  for (int j = 0; j < 4; ++j) {
    const int g = tid + j * 1024;
    if (g < ng) {
      const int4 p = vp4[g]; const int4 b = vb4[g]; const float4 w = vw4[g];
      const int k = j * 4;
      #define STAGE(q, PP, BB, WW) { \
        const unsigned short hw = __builtin_bit_cast(unsigned short, (_Float16)(WW)); \
        e[k + q] = (unsigned)(PP) | (((unsigned)(BB) & 31u) << 14) | (((unsigned)hw >> 3) << 19); \
        bu16[k + q] = (unsigned short)((unsigned)(BB) >> BBITS); \
        rr[k + q] = (unsigned short)atomicAdd(&h[(unsigned)(BB) >> BBITS], 1u); }
      STAGE(0, p.x, b.x, w.x) STAGE(1, p.y, b.y, w.y)
      STAGE(2, p.z, b.z, w.z) STAGE(3, p.w, b.w, w.w)
      #undef STAGE
    }
  }
  // robustness tail (cnt%4, zero for nv=4M): straight to overflow list
  const int tail0 = ng * 4;
  if (tid < cnt - tail0) {
    const int gi = c0 + tail0 + tid;
    unsigned o = atomicAdd(ovrcnt, 1u);
    if (o < OVR_CAP)
      ovrlist[o] = make_uint2((unsigned)vp[gi] | ((unsigned)vb[gi] << 14),
                              __float_as_uint(vw[gi]));
  }
  __syncthreads();

  // single-wave exclusive scan of h -> lstart (wave 0: 17 buckets/lane + shfl)
  if (tid < 64) {
    const int lo = tid * 17, hi = min(NBUCK, lo + 17);   // 64*17=1088 >= 1035
    unsigned s = 0;
    for (int i = lo; i < hi; ++i) s += h[i];
    unsigned inc = s;
    #pragma unroll
    for (int d = 1; d < 64; d <<= 1) {
      const unsigned v = __shfl_up(inc, d);
      if (tid >= d) inc += v;
    }
    unsigned run = inc - s;                               // exclusive base
    for (int i = lo; i < hi; ++i) { lstart[i] = run; run += h[i]; }
  }
  __syncthreads();
  // one global reservation per non-empty bucket
  for (int i = tid; i < NBUCK; i += 1024)
    cur[i] = (h[i] != 0u) ? atomicAdd(&globcur[i], h[i]) : 0u;
  __syncthreads();

  // place into LDS, bucket-clustered (plain b32 writes; rank from registers)
  #pragma unroll
  for (int j = 0; j < 4; ++j) {
    const int g = tid + j * 1024;
    if (g < ng) {
      #pragma unroll
      for (int q = 0; q < 4; ++q) {
        const int k = j * 4 + q;
        lds[lstart[bu16[k]] + (unsigned)rr[k]] = e[k];
      }
    }
  }
  __syncthreads();

  // flush: wave w -> buckets w, w+16, ...; contiguous LDS -> contiguous global
  const int wid = tid >> 6, lane = tid & 63;
  for (int bu = wid; bu < NBUCK; bu += 16) {
    const unsigned c = h[bu];
    if (c == 0u) continue;                       // wave-uniform branch
    const unsigned gb = cur[bu], lb = lstart[bu];
    for (unsigned s = lane; s < c; s += 64) {
      const unsigned E = lds[lb + s];
      const unsigned g = gb + s;
      if (g < CAPB) {
        sorted[(size_t)bu * CAPB + g] = E;
      } else {
        unsigned o = atomicAdd(ovrcnt, 1u);
        if (o < OVR_CAP) {
          const unsigned pp  = E & 0x3FFFu;
          const unsigned bin = ((unsigned)bu << BBITS) + ((E >> 14) & 31u);
          ovrlist[o] = make_uint2(pp | (bin << 14), __float_as_uint(w_from_top13(E)));
        }
      }
    }
  }
}

// ---------- per-bucket spmm + fused overflow merge + transposed epilogue ------
// Overflow entries for bucket bu are either pre-existing (scatter) or pushed by
// this block itself during placement (always own-bucket) => merging into the
// LDS tile before the tile->out write is ordering-safe. k_overflow eliminated.
__global__ __launch_bounds__(512) void k_spmm_static(
    const unsigned* __restrict__ sorted, const unsigned* __restrict__ globcur,
    const float* __restrict__ xT, float* __restrict__ out,
    unsigned* __restrict__ ovrcnt, uint2* __restrict__ ovrlist) {
  __shared__ unsigned sv[32 * SSTR];       // 24,832 B
  __shared__ unsigned cur[32];
  __shared__ float tile[32][33];           // [bin][map], +1 pad
  const int tid = threadIdx.x;
  const int bu = blockIdx.x;
  const int n = min((int)globcur[bu], CAPB);

  if (tid < 32) cur[tid] = 0u;
  __syncthreads();

  // place: 4 votes per 16B load, 1 LDS atomic + 1 b32 write per vote
  const uint4* src = (const uint4*)(sorted + (size_t)bu * CAPB);  // CAPB%4==0
  const int nq = n >> 2;
  #define PLACE(E) { \
    const unsigned fb = ((E) >> 14) & 31u; \
    const unsigned s = atomicAdd(&cur[fb], 1u); \
    if (s < SLAB) sv[fb * SSTR + s] = (E) & 0xFFF83FFFu; \
    else { \
      unsigned o = atomicAdd(ovrcnt, 1u); \
      if (o < OVR_CAP) \
        ovrlist[o] = make_uint2(((E) & 0x3FFFu) | ((((unsigned)bu << BBITS) + fb) << 14), \
                                __float_as_uint(w_from_top13(E))); } }
  for (int i = tid; i < nq; i += 512) {
    const uint4 q = src[i];
    PLACE(q.x) PLACE(q.y) PLACE(q.z) PLACE(q.w)
  }
  if (tid < (n & 3)) {                     // tail votes (<=3)
    const unsigned E = sorted[(size_t)bu * CAPB + (n & ~3) + tid];
    PLACE(E)
  }
  #undef PLACE
  __syncthreads();

  // compute: wave wv -> bins [wv*4, wv*4+4); halves take consecutive pairs
  // via ds_read_b64; weight = f16 in entry bits [16,32).
  #define WDEC(E) ((float)__builtin_bit_cast(_Float16, (unsigned short)((E) >> 16)))
  const int wv = tid >> 6, lane = tid & 63, half = lane >> 5, m = lane & 31;
  #pragma unroll
  for (int s4 = 0; s4 < 4; ++s4) {
    const int b = wv * 4 + s4;
    const int cnt = min((int)cur[b], SLAB);
    const unsigned* seg = &sv[b * SSTR];
    float acc = 0.0f;
    int base = 0;
    for (; base + 8 <= cnt; base += 8) {
      const uint2 a = *(const uint2*)(seg + base + 2 * half);
      const uint2 c = *(const uint2*)(seg + base + 4 + 2 * half);
      acc += WDEC(a.x) * xT[(a.x & 0x3FFFu) * 32 + m];
      acc += WDEC(a.y) * xT[(a.y & 0x3FFFu) * 32 + m];
      acc += WDEC(c.x) * xT[(c.x & 0x3FFFu) * 32 + m];
      acc += WDEC(c.y) * xT[(c.y & 0x3FFFu) * 32 + m];
    }
    for (; base + 4 <= cnt; base += 4) {
      const uint2 a = *(const uint2*)(seg + base + 2 * half);
      acc += WDEC(a.x) * xT[(a.x & 0x3FFFu) * 32 + m];
      acc += WDEC(a.y) * xT[(a.y & 0x3FFFu) * 32 + m];
    }
    if (half == 0) {                       // scalar tail (<=3 votes)
      for (int j = base; j < cnt; ++j) {
        const unsigned E = seg[j];
        acc += WDEC(E) * xT[(E & 0x3FFFu) * 32 + m];
      }
    }
    acc += __shfl_xor(acc, 32);            // combine halves
    if (lane < 32)                         // stage result in tile
      tile[b][m] = acc * INV_NORM;
  }
  #undef WDEC
  __syncthreads();

  // fused overflow merge: rare entries for THIS bucket -> atomicAdd into tile
  {
    unsigned nov = *ovrcnt;
    nov = nov < (unsigned)OVR_CAP ? nov : (unsigned)OVR_CAP;
    if (nov) {
      for (unsigned idx = tid; idx < nov * 32u; idx += 512u) {
        const unsigned vi = idx >> 5, m2 = idx & 31u;
        const uint2 vv = ovrlist[vi];
        const unsigned bin = vv.x >> 14;
        if ((bin >> BBITS) == (unsigned)bu) {
          atomicAdd(&tile[bin & 31u][m2],
                    __uint_as_float(vv.y) * xT[(vv.x & 0x3FFFu) * 32 + m2] * INV_NORM);
        }
      }
      __syncthreads();
    }
  }

  // fused transposed write: out[m][bin_base + c] for c in [0,32).
  {
    const int row  = tid >> 4;             // 0..31 (map index)
    const int col2 = (tid & 15) * 2;       // 0,2,..,30 (bin offset)
    const int gb0  = bu << BBITS;
    const float2 v2 = make_float2(tile[col2][row], tile[col2 + 1][row]);
    *(float2*)(out + (size_t)row * NBINS + gb0 + col2) = v2;
  }
}

// ---------- fallback (ws too small): R1 LDS-histogram version -----------------
__global__ __launch_bounds__(1024) void ht_fallback(const float* __restrict__ x,
                                                    const int* __restrict__ vp,
                                                    const int* __restrict__ vb,
                                                    const float* __restrict__ vw,
                                                    float* __restrict__ out, int nv) {
  __shared__ float hist[NBINS];
  for (int i = threadIdx.x; i < NBINS; i += 1024) hist[i] = 0.0f;
  __syncthreads();
  const int map = blockIdx.x >> 3, chunk = blockIdx.x & 7;
  const float* xm = x + map * IM_HW;
  const int per = (nv + 7) / 8;
  const int start = chunk * per, end = min(nv, start + per);
  for (int i = start + (int)threadIdx.x; i < end; i += 1024)
    atomicAdd(&hist[vb[i]], xm[vp[i]] * vw[i]);
  __syncthreads();
  float* om = out + map * NBINS;
  for (int i = threadIdx.x; i < NBINS; i += 1024)
    atomicAdd(&om[i], hist[i] * INV_NORM);
}

extern "C" void kernel_launch(void* const* d_in, const int* in_sizes, int n_in,
                              void* d_out, int out_size, void* d_ws, size_t ws_size,
                              hipStream_t stream) {
  const float* x  = (const float*)d_in[0];
  const int*   vp = (const int*)d_in[1];
  const int*   vb = (const int*)d_in[2];
  const float* vw = (const float*)d_in[3];
  float* out = (float*)d_out;
  const int nv = in_sizes[1];

  // ws layout (all sections 16B-aligned)
  char* w = (char*)d_ws;
  unsigned* sorted  = (unsigned*)w; w += (size_t)NBUCK * CAPB * 4;   // 18.0 MB
  float*    xT      = (float*)w;    w += (size_t)IM_HW * NMAPS * 4;  // 2 MB
  uint2*    ovrlist = (uint2*)w;    w += (size_t)OVR_CAP * 8;        // 64 KB
  unsigned* globcur = (unsigned*)w; w += (size_t)NBUCK * 4;          // 4140 B
  unsigned* ovrcnt  = (unsigned*)w; w += 16;                         // pad to 16
  const size_t need = (size_t)(w - (char*)d_ws);

  if (ws_size >= need) {
    // zero globcur + ovrcnt (one contiguous region)
    hipMemsetAsync(globcur, 0, (size_t)NBUCK * 4 + 16, stream);
    k_scatter_bucket<<<NB_SCAT, 1024, 0, stream>>>(x, xT, vp, vb, vw, nv, globcur,
                                                   ovrcnt, ovrlist, sorted);
    k_spmm_static<<<NBUCK, 512, 0, stream>>>(sorted, globcur, xT, out,
                                             ovrcnt, ovrlist);
  } else {
    hipMemsetAsync(out, 0, (size_t)out_size * sizeof(float), stream);
    ht_fallback<<<256, 1024, 0, stream>>>(x, vp, vb, vw, out, nv);
  }
}

// Round 15
// 150.989 us; speedup vs baseline: 1.3668x; 1.0256x over previous
//
#include <hip/hip_runtime.h>
#include <stdint.h>

// Problem constants
#define IM_HW   16384            // 128*128 pixels
#define NBINS   33120            // 184*180
#define NMAPS   32               // b*c = 2*16
#define INV_NORM (1.0f / 128.0f)

#define BBITS   5                // bins per bucket = 32
#define NBUCK   1035             // NBINS/32 exactly
#define CAPB    4352             // slots/bucket (mean 3865, +7.8 sigma), %4==0
#define SLAB    192              // LDS slots per fine bin (mean 120.8, +6.5 sigma)
#define SSTR    194              // slab stride (even: b64-aligned; ≡2 mod 32: bank spread)
#define NB_SCAT 256              // scatter blocks
#define OVR_CAP 8192             // overflow list capacity (votes)

// Weight encoding: top-13 bits of the f16 bit pattern, stored at [19,32).
__device__ __forceinline__ float w_from_top13(unsigned e) {   // e>>19 = top13
  const unsigned short hb = (unsigned short)((e >> 19) << 3);
  return (float)__builtin_bit_cast(_Float16, hb);
}
__device__ __forceinline__ float f16u(unsigned short h) {
  return (float)__builtin_bit_cast(_Float16, h);
}

// ---------- bucket scatter (R8-proven) + fused xT(f16) transpose prologue -----
__global__ __launch_bounds__(1024) void k_scatter_bucket(
    const float* __restrict__ x, unsigned short* __restrict__ xT2,
    const int* __restrict__ vp, const int* __restrict__ vb,
    const float* __restrict__ vw, int nv,
    unsigned* __restrict__ globcur,      // [NBUCK] bucket fills (pre-zeroed)
    unsigned* __restrict__ ovrcnt,       // [1] overflow count (pre-zeroed)
    uint2*   __restrict__ ovrlist,       // [OVR_CAP]
    unsigned* __restrict__ sorted) {     // [NBUCK*CAPB] 4B entries
  __shared__ unsigned h[NBUCK];          // per-bucket counts
  __shared__ unsigned lstart[NBUCK];     // local exclusive starts
  __shared__ unsigned cur[NBUCK];        // global reserved bases
  __shared__ unsigned lds[16384];        // block-local bucket-sorted votes (64KB)

  const int tid = threadIdx.x;

  // fused transpose+cvt: x[32][16384] -> xT2[16384][32] f16 (write-coalesced)
  {
    const int base = blockIdx.x * 2048;          // 256*2048 = 524288 = 32*16384
    #pragma unroll
    for (int k = 0; k < 2; ++k) {
      const int i = base + k * 1024 + tid;       // i = p*32 + m
      const int m = i & 31, p = i >> 5;
      xT2[i] = __builtin_bit_cast(unsigned short, (_Float16)x[m * IM_HW + p]);
    }
  }

  const int chunk = (((nv + NB_SCAT - 1) / NB_SCAT) + 3) & ~3;   // 4-aligned
  const int c0 = blockIdx.x * chunk;
  const int c1 = min(nv, c0 + chunk);
  const int cnt = (c1 > c0) ? (c1 - c0) : 0;    // <= 15628 <= 16384

  for (int i = tid; i < NBUCK; i += 1024) h[i] = 0u;
  __syncthreads();

  // stage + rank (1 LDS atomic per vote; return value = within-bucket rank)
  unsigned e[16];
  unsigned short rr[16], bu16[16];
  const int ng = cnt >> 2;                       // groups of 4 votes
  const int4*   vp4 = (const int4*)(vp + c0);
  const int4*   vb4 = (const int4*)(vb + c0);
  const float4* vw4 = (const float4*)(vw + c0);
  #pragma unroll
  for (int j = 0; j < 4; ++j) {
    const int g = tid + j * 1024;
    if (g < ng) {
      const int4 p = vp4[g]; const int4 b = vb4[g]; const float4 w = vw4[g];
      const int k = j * 4;
      #define STAGE(q, PP, BB, WW) { \
        const unsigned short hw = __builtin_bit_cast(unsigned short, (_Float16)(WW)); \
        e[k + q] = (unsigned)(PP) | (((unsigned)(BB) & 31u) << 14) | (((unsigned)hw >> 3) << 19); \
        bu16[k + q] = (unsigned short)((unsigned)(BB) >> BBITS); \
        rr[k + q] = (unsigned short)atomicAdd(&h[(unsigned)(BB) >> BBITS], 1u); }
      STAGE(0, p.x, b.x, w.x) STAGE(1, p.y, b.y, w.y)
      STAGE(2, p.z, b.z, w.z) STAGE(3, p.w, b.w, w.w)
      #undef STAGE
    }
  }
  // robustness tail (cnt%4, zero for nv=4M): straight to overflow list
  const int tail0 = ng * 4;
  if (tid < cnt - tail0) {
    const int gi = c0 + tail0 + tid;
    unsigned o = atomicAdd(ovrcnt, 1u);
    if (o < OVR_CAP)
      ovrlist[o] = make_uint2((unsigned)vp[gi] | ((unsigned)vb[gi] << 14),
                              __float_as_uint(vw[gi]));
  }
  __syncthreads();

  // single-wave exclusive scan of h -> lstart (wave 0: 17 buckets/lane + shfl)
  if (tid < 64) {
    const int lo = tid * 17, hi = min(NBUCK, lo + 17);   // 64*17=1088 >= 1035
    unsigned s = 0;
    for (int i = lo; i < hi; ++i) s += h[i];
    unsigned inc = s;
    #pragma unroll
    for (int d = 1; d < 64; d <<= 1) {
      const unsigned v = __shfl_up(inc, d);
      if (tid >= d) inc += v;
    }
    unsigned run = inc - s;                               // exclusive base
    for (int i = lo; i < hi; ++i) { lstart[i] = run; run += h[i]; }
  }
  __syncthreads();
  // one global reservation per non-empty bucket
  for (int i = tid; i < NBUCK; i += 1024)
    cur[i] = (h[i] != 0u) ? atomicAdd(&globcur[i], h[i]) : 0u;
  __syncthreads();

  // place into LDS, bucket-clustered (plain b32 writes; rank from registers)
  #pragma unroll
  for (int j = 0; j < 4; ++j) {
    const int g = tid + j * 1024;
    if (g < ng) {
      #pragma unroll
      for (int q = 0; q < 4; ++q) {
        const int k = j * 4 + q;
        lds[lstart[bu16[k]] + (unsigned)rr[k]] = e[k];
      }
    }
  }
  __syncthreads();

  // flush: wave w -> buckets w, w+16, ...; contiguous LDS -> contiguous global
  const int wid = tid >> 6, lane = tid & 63;
  for (int bu = wid; bu < NBUCK; bu += 16) {
    const unsigned c = h[bu];
    if (c == 0u) continue;                       // wave-uniform branch
    const unsigned gb = cur[bu], lb = lstart[bu];
    for (unsigned s = lane; s < c; s += 64) {
      const unsigned E = lds[lb + s];
      const unsigned g = gb + s;
      if (g < CAPB) {
        sorted[(size_t)bu * CAPB + g] = E;
      } else {
        unsigned o = atomicAdd(ovrcnt, 1u);
        if (o < OVR_CAP) {
          const unsigned pp  = E & 0x3FFFu;
          const unsigned bin = ((unsigned)bu << BBITS) + ((E >> 14) & 31u);
          ovrlist[o] = make_uint2(pp | (bin << 14), __float_as_uint(w_from_top13(E)));
        }
      }
    }
  }
}

// ---------- per-bucket spmm + fused overflow merge + transposed epilogue ------
// Compute lane layout: 64 lanes = 4 vote-slots (q) x 16 map-pairs (mp); one
// 4B gather (uint = 2 f16 maps) + 2 fma per vote-lane. Placement unchanged.
__global__ __launch_bounds__(512) void k_spmm_static(
    const unsigned* __restrict__ sorted, const unsigned* __restrict__ globcur,
    const unsigned short* __restrict__ xT2, float* __restrict__ out,
    unsigned* __restrict__ ovrcnt, uint2* __restrict__ ovrlist) {
  __shared__ unsigned sv[32 * SSTR];       // 24,832 B
  __shared__ unsigned cur[32];
  __shared__ float tile[32][33];           // [bin][map], +1 pad
  const int tid = threadIdx.x;
  const int bu = blockIdx.x;
  const int n = min((int)globcur[bu], CAPB);

  if (tid < 32) cur[tid] = 0u;
  __syncthreads();

  // place: 4 votes per 16B load, 1 LDS atomic + 1 b32 write per vote
  const uint4* src = (const uint4*)(sorted + (size_t)bu * CAPB);  // CAPB%4==0
  const int nq = n >> 2;
  #define PLACE(E) { \
    const unsigned fb = ((E) >> 14) & 31u; \
    const unsigned s = atomicAdd(&cur[fb], 1u); \
    if (s < SLAB) sv[fb * SSTR + s] = (E) & 0xFFF83FFFu; \
    else { \
      unsigned o = atomicAdd(ovrcnt, 1u); \
      if (o < OVR_CAP) \
        ovrlist[o] = make_uint2(((E) & 0x3FFFu) | ((((unsigned)bu << BBITS) + fb) << 14), \
                                __float_as_uint(w_from_top13(E))); } }
  for (int i = tid; i < nq; i += 512) {
    const uint4 q = src[i];
    PLACE(q.x) PLACE(q.y) PLACE(q.z) PLACE(q.w)
  }
  if (tid < (n & 3)) {                     // tail votes (<=3)
    const unsigned E = sorted[(size_t)bu * CAPB + (n & ~3) + tid];
    PLACE(E)
  }
  #undef PLACE
  __syncthreads();

  // compute: wave wv -> bins [wv*4, wv*4+4). Quarter q takes votes q, q+4, ...
  // (uint2 pairs in main loop); per vote one uint load = 2 f16 maps + 2 fma.
  #define WDEC(E) ((float)__builtin_bit_cast(_Float16, (unsigned short)((E) >> 16)))
  const unsigned* xh2 = (const unsigned*)xT2;    // [16384][16] map-pairs
  const int wv = tid >> 6, lane = tid & 63;
  const int q = lane >> 4, mp = lane & 15;
  #pragma unroll
  for (int s4 = 0; s4 < 4; ++s4) {
    const int b = wv * 4 + s4;
    const int cnt = min((int)cur[b], SLAB);
    const unsigned* seg = &sv[b * SSTR];
    float acc0 = 0.0f, acc1 = 0.0f;
    int base = 0;
    for (; base + 8 <= cnt; base += 8) {   // 8 votes/iter: quarter q -> 2 votes
      const uint2 a = *(const uint2*)(seg + base + 2 * q);
      {
        const unsigned xv = xh2[(a.x & 0x3FFFu) * 16 + mp];
        const float w = WDEC(a.x);
        acc0 += w * f16u((unsigned short)(xv & 0xFFFFu));
        acc1 += w * f16u((unsigned short)(xv >> 16));
      }
      {
        const unsigned xv = xh2[(a.y & 0x3FFFu) * 16 + mp];
        const float w = WDEC(a.y);
        acc0 += w * f16u((unsigned short)(xv & 0xFFFFu));
        acc1 += w * f16u((unsigned short)(xv >> 16));
      }
    }
    for (int j = base + q; j < cnt; j += 4) {    // tail: <=7 votes, stride-4
      const unsigned E = seg[j];
      const unsigned xv = xh2[(E & 0x3FFFu) * 16 + mp];
      const float w = WDEC(E);
      acc0 += w * f16u((unsigned short)(xv & 0xFFFFu));
      acc1 += w * f16u((unsigned short)(xv >> 16));
    }
    // combine the 4 quarters (lanes mp, mp+16, mp+32, mp+48)
    acc0 += __shfl_xor(acc0, 16); acc0 += __shfl_xor(acc0, 32);
    acc1 += __shfl_xor(acc1, 16); acc1 += __shfl_xor(acc1, 32);
    if (lane < 16) {
      tile[b][2 * mp]     = acc0 * INV_NORM;
      tile[b][2 * mp + 1] = acc1 * INV_NORM;
    }
  }
  #undef WDEC
  __syncthreads();

  // fused overflow merge: rare entries for THIS bucket -> atomicAdd into tile
  {
    unsigned nov = *ovrcnt;
    nov = nov < (unsigned)OVR_CAP ? nov : (unsigned)OVR_CAP;
    if (nov) {
      for (unsigned idx = tid; idx < nov * 32u; idx += 512u) {
        const unsigned vi = idx >> 5, m2 = idx & 31u;
        const uint2 vv = ovrlist[vi];
        const unsigned bin = vv.x >> 14;
        if ((bin >> BBITS) == (unsigned)bu) {
          const float xv = f16u(xT2[(vv.x & 0x3FFFu) * 32 + m2]);
          atomicAdd(&tile[bin & 31u][m2],
                    __uint_as_float(vv.y) * xv * INV_NORM);
        }
      }
      __syncthreads();
    }
  }

  // fused transposed write: out[m][bin_base + c] for c in [0,32).
  {
    const int row  = tid >> 4;             // 0..31 (map index)
    const int col2 = (tid & 15) * 2;       // 0,2,..,30 (bin offset)
    const int gb0  = bu << BBITS;
    const float2 v2 = make_float2(tile[col2][row], tile[col2 + 1][row]);
    *(float2*)(out + (size_t)row * NBINS + gb0 + col2) = v2;
  }
}

// ---------- fallback (ws too small): R1 LDS-histogram version -----------------
__global__ __launch_bounds__(1024) void ht_fallback(const float* __restrict__ x,
                                                    const int* __restrict__ vp,
                                                    const int* __restrict__ vb,
                                                    const float* __restrict__ vw,
                                                    float* __restrict__ out, int nv) {
  __shared__ float hist[NBINS];
  for (int i = threadIdx.x; i < NBINS; i += 1024) hist[i] = 0.0f;
  __syncthreads();
  const int map = blockIdx.x >> 3, chunk = blockIdx.x & 7;
  const float* xm = x + map * IM_HW;
  const int per = (nv + 7) / 8;
  const int start = chunk * per, end = min(nv, start + per);
  for (int i = start + (int)threadIdx.x; i < end; i += 1024)
    atomicAdd(&hist[vb[i]], xm[vp[i]] * vw[i]);
  __syncthreads();
  float* om = out + map * NBINS;
  for (int i = threadIdx.x; i < NBINS; i += 1024)
    atomicAdd(&om[i], hist[i] * INV_NORM);
}

extern "C" void kernel_launch(void* const* d_in, const int* in_sizes, int n_in,
                              void* d_out, int out_size, void* d_ws, size_t ws_size,
                              hipStream_t stream) {
  const float* x  = (const float*)d_in[0];
  const int*   vp = (const int*)d_in[1];
  const int*   vb = (const int*)d_in[2];
  const float* vw = (const float*)d_in[3];
  float* out = (float*)d_out;
  const int nv = in_sizes[1];

  // ws layout (all sections 16B-aligned)
  char* w = (char*)d_ws;
  unsigned*       sorted  = (unsigned*)w;       w += (size_t)NBUCK * CAPB * 4; // 18.0 MB
  unsigned short* xT2     = (unsigned short*)w; w += (size_t)IM_HW * NMAPS * 2; // 1 MB
  uint2*          ovrlist = (uint2*)w;          w += (size_t)OVR_CAP * 8;      // 64 KB
  unsigned*       globcur = (unsigned*)w;       w += (size_t)NBUCK * 4;        // 4140 B
  unsigned*       ovrcnt  = (unsigned*)w;       w += 16;                       // pad
  const size_t need = (size_t)(w - (char*)d_ws);

  if (ws_size >= need) {
    // zero globcur + ovrcnt (one contiguous region)
    hipMemsetAsync(globcur, 0, (size_t)NBUCK * 4 + 16, stream);
    k_scatter_bucket<<<NB_SCAT, 1024, 0, stream>>>(x, xT2, vp, vb, vw, nv, globcur,
                                                   ovrcnt, ovrlist, sorted);
    k_spmm_static<<<NBUCK, 512, 0, stream>>>(sorted, globcur, xT2, out,
                                             ovrcnt, ovrlist);
  } else {
    hipMemsetAsync(out, 0, (size_t)out_size * sizeof(float), stream);
    ht_fallback<<<256, 1024, 0, stream>>>(x, vp, vb, vw, out, nv);
  }
}